// Round 16
// baseline (128.029 us; speedup 1.0000x reference)
//
#include <hip/hip_runtime.h>
#include <stdint.h>

#define DIM 768
#define D_STATE 16
#define D_CONV 4
#define DT_RANK 32
#define D_INNER 1536
#define BATCH 2
#define SEQ 1024
#define BL (BATCH * SEQ)   // 2048
#define E2 (2 * D_INNER)   // 3072
#define NCHUNK 64
#define TC (SEQ / NCHUNK)  // 16 steps per chunk
#define XKS 8              // split-K factor for x_dbl GEMM
#define XKC (D_INNER / XKS) // 192

typedef __attribute__((ext_vector_type(8))) __bf16 bf16x8;
typedef __attribute__((ext_vector_type(4))) float f32x4;
typedef __attribute__((ext_vector_type(8))) unsigned short u16x8;

__device__ __forceinline__ float silu_f(float v) {
    return v / (1.0f + __expf(-v));
}
// fast softplus: hardware exp/log path
__device__ __forceinline__ float softplus_f(float v) {
    return fmaxf(v, 0.0f) + __logf(1.0f + __expf(-fabsf(v)));
}
__device__ __forceinline__ unsigned short f2bf(float f) {
    uint32_t u = __float_as_uint(f);
    u += 0x7FFFu + ((u >> 16) & 1u);          // round-to-nearest-even
    return (unsigned short)(u >> 16);
}
__device__ __forceinline__ float bf2f(unsigned short u) {
    return __uint_as_float((uint32_t)u << 16);
}
// global -> LDS direct copy, 16B per lane. LDS dest: wave-uniform base + lane*16.
__device__ __forceinline__ void gload_lds16(const void* g, void* l) {
    __builtin_amdgcn_global_load_lds(
        (const __attribute__((address_space(1))) unsigned int*)(uintptr_t)g,
        (__attribute__((address_space(3))) unsigned int*)(uint32_t)(uintptr_t)l,
        16, 0, 0);
}

// ---------------------------------------------------------------------------
// Fused f32->bf16 conversion: W_in, x, W_out, W_x in one dispatch.
// ---------------------------------------------------------------------------
__global__ __launch_bounds__(256) void cvt4_kernel(
    const float* __restrict__ s0, unsigned short* __restrict__ d0, int n0,
    const float* __restrict__ s1, unsigned short* __restrict__ d1, int n1,
    const float* __restrict__ s2, unsigned short* __restrict__ d2, int n2,
    const float* __restrict__ s3, unsigned short* __restrict__ d3, int n3)
{
    int i = blockIdx.x * 256 + threadIdx.x;
    const float* s; unsigned short* d;
    if (i < n0)                          { s = s0; d = d0; }
    else if ((i -= n0) < n1)             { s = s1; d = d1; }
    else if ((i -= n1) < n2)             { s = s2; d = d2; }
    else { i -= n2; if (i >= n3) return;   s = s3; d = d3; }
    const f32x4 a = ((const f32x4*)s)[2 * i];
    const f32x4 b = ((const f32x4*)s)[2 * i + 1];
    u16x8 o;
#pragma unroll
    for (int j = 0; j < 4; ++j) { o[j] = f2bf(a[j]); o[4 + j] = f2bf(b[j]); }
    ((u16x8*)d)[i] = o;
}

// ---------------------------------------------------------------------------
// bf16 MFMA GEMM (R14-proven form, 2D grid, no swizzle).
// 4 waves (2x2), 16x16x32 MFMA, 2-phase double-buffered LDS.
// EPI 0: f32 out.  EPI 2: acc + X[row*ldx+col] -> f32 out.  EPI 3: bf16 out.
// ---------------------------------------------------------------------------
template <int BM, int BN, int EPI>
__global__ __launch_bounds__(256) void gemm_bf16(
    const unsigned short* __restrict__ A, const unsigned short* __restrict__ B,
    void* __restrict__ C, int ldc,
    const float* __restrict__ X, int ldx, int K)
{
    constexpr int NROW = BM + BN;      // staged rows (A then B), 32 bf16 cols
    constexpr int RW = NROW / 4;       // rows per wave
    constexpr int NC = RW / 16;        // gload_lds16 calls per wave per tile
    constexpr int FM = BM / 32;        // frag rows per wave (2x2 wave grid)
    constexpr int FN = BN / 32;
    __shared__ __align__(16) unsigned short S[2][NROW * 32];
    const int tid = threadIdx.x;
    const int wid = tid >> 6;
    const int lane = tid & 63;
    const int wr = wid >> 1, wc = wid & 1;
    const int bm = blockIdx.y * BM, bn = blockIdx.x * BN;

    const int lrow = lane >> 2;
    const int scol = (lane & 3) * 8;
    const unsigned short* gsrc[NC];
#pragma unroll
    for (int c = 0; c < NC; ++c) {
        const int rowbase = wid * RW + c * 16;       // wave-uniform, %16==0
        const int grow = rowbase + lrow;
        gsrc[c] = (rowbase < BM)
            ? A + (size_t)(bm + grow) * K + scol
            : B + (size_t)(bn + grow - BM) * K + scol;
    }

    const int fr = lane & 15;
    const int fq = lane >> 4;
    f32x4 acc[FM][FN] = {};

    auto STAGE = [&](int nb, int k0) {
#pragma unroll
        for (int c = 0; c < NC; ++c)
            gload_lds16(gsrc[c] + k0, &S[nb][(wid * RW + c * 16) * 32]);
    };
    auto COMPUTE = [&](int cb) {
        bf16x8 af[FM], bfr[FN];
#pragma unroll
        for (int m = 0; m < FM; ++m)
            af[m] = *(const bf16x8*)&S[cb][(wr * (BM / 2) + m * 16 + fr) * 32 + fq * 8];
#pragma unroll
        for (int n = 0; n < FN; ++n)
            bfr[n] = *(const bf16x8*)&S[cb][(BM + wc * (BN / 2) + n * 16 + fr) * 32 + fq * 8];
#pragma unroll
        for (int m = 0; m < FM; ++m)
#pragma unroll
            for (int n = 0; n < FN; ++n)
                acc[m][n] = __builtin_amdgcn_mfma_f32_16x16x32_bf16(
                    af[m], bfr[n], acc[m][n], 0, 0, 0);
    };

    STAGE(0, 0);
    asm volatile("s_waitcnt vmcnt(0)" ::: "memory");
    __builtin_amdgcn_s_barrier();
    int cur = 0;
    for (int k0 = 32; k0 < K; k0 += 32) {
        STAGE(cur ^ 1, k0);      // next tile's loads fly under compute
        COMPUTE(cur);
        asm volatile("s_waitcnt vmcnt(0)" ::: "memory");
        __builtin_amdgcn_s_barrier();
        cur ^= 1;
    }
    COMPUTE(cur);

#pragma unroll
    for (int m = 0; m < FM; ++m) {
#pragma unroll
        for (int n = 0; n < FN; ++n) {
            const int col = bn + wc * (BN / 2) + n * 16 + fr;
#pragma unroll
            for (int r = 0; r < 4; ++r) {
                const int row = bm + wr * (BM / 2) + m * 16 + fq * 4 + r;
                float o = acc[m][n][r];
                if (EPI == 0) {
                    ((float*)C)[(size_t)row * ldc + col] = o;
                } else if (EPI == 2) {
                    o += X[(size_t)row * ldx + col];
                    ((float*)C)[(size_t)row * ldc + col] = o;
                } else {
                    ((unsigned short*)C)[(size_t)row * ldc + col] = f2bf(o);
                }
            }
        }
    }
}

// ---------------------------------------------------------------------------
// x_dbl GEMM, split-K: part[ks][M][64] = xcsb[M, ks*192:+192] @ W_x^T chunk.
// ---------------------------------------------------------------------------
__global__ __launch_bounds__(256) void xdbl_gemm(
    const unsigned short* __restrict__ xcsb,
    const unsigned short* __restrict__ W_x_b,
    float* __restrict__ part)
{
    constexpr int BM = 128, NROW = BM + 64, RW = NROW / 4, NC = RW / 16;
    __shared__ __align__(16) unsigned short S[2][NROW * 32];
    const int tid = threadIdx.x;
    const int wid = tid >> 6, lane = tid & 63;
    const int wr = wid >> 1, wc = wid & 1;
    const int bm = blockIdx.y * BM;
    const int kb = blockIdx.x * XKC;
    const int lrow = lane >> 2, scol = (lane & 3) * 8;
    const unsigned short* gsrc[NC];
#pragma unroll
    for (int c = 0; c < NC; ++c) {
        const int rowbase = wid * RW + c * 16;
        const int grow = rowbase + lrow;
        gsrc[c] = (rowbase < BM)
            ? xcsb + (size_t)(bm + grow) * D_INNER + kb + scol
            : W_x_b + (size_t)(grow - BM) * D_INNER + kb + scol;
    }
    const int fr = lane & 15, fq = lane >> 4;
    f32x4 acc[4][2] = {};
    auto STAGE = [&](int nb, int k0) {
#pragma unroll
        for (int c = 0; c < NC; ++c)
            gload_lds16(gsrc[c] + k0, &S[nb][(wid * RW + c * 16) * 32]);
    };
    auto COMPUTE = [&](int cb) {
        bf16x8 af[4], bfr[2];
#pragma unroll
        for (int m = 0; m < 4; ++m)
            af[m] = *(const bf16x8*)&S[cb][(wr * 64 + m * 16 + fr) * 32 + fq * 8];
#pragma unroll
        for (int n = 0; n < 2; ++n)
            bfr[n] = *(const bf16x8*)&S[cb][(BM + wc * 32 + n * 16 + fr) * 32 + fq * 8];
#pragma unroll
        for (int m = 0; m < 4; ++m)
#pragma unroll
            for (int n = 0; n < 2; ++n)
                acc[m][n] = __builtin_amdgcn_mfma_f32_16x16x32_bf16(
                    af[m], bfr[n], acc[m][n], 0, 0, 0);
    };
    STAGE(0, 0);
    asm volatile("s_waitcnt vmcnt(0)" ::: "memory");
    __builtin_amdgcn_s_barrier();
    int cur = 0;
    for (int k0 = 32; k0 < XKC; k0 += 32) {
        STAGE(cur ^ 1, k0);
        COMPUTE(cur);
        asm volatile("s_waitcnt vmcnt(0)" ::: "memory");
        __builtin_amdgcn_s_barrier();
        cur ^= 1;
    }
    COMPUTE(cur);
    float* P = part + (size_t)blockIdx.x * BL * 64;
#pragma unroll
    for (int m = 0; m < 4; ++m)
#pragma unroll
        for (int n = 0; n < 2; ++n) {
            const int col = wc * 32 + n * 16 + fr;
#pragma unroll
            for (int r = 0; r < 4; ++r) {
                const int row = bm + wr * 64 + m * 16 + fq * 4 + r;
                P[(size_t)row * 64 + col] = acc[m][n][r];
            }
        }
}

// ---------------------------------------------------------------------------
// Fused: reduce split-K partials -> xdbl fp32 (B,C for scan), then the dt
// projection dt = softplus(dt_lr @ W_dt^T + 2 b_dt) -> bf16 (dt_lr in LDS).
// ---------------------------------------------------------------------------
__global__ __launch_bounds__(256) void xdbl_reduce_dt(
    const float* __restrict__ part, float* __restrict__ xdbl,
    const float* __restrict__ W_dt, const float* __restrict__ b_dt,
    unsigned short* __restrict__ dtgb)
{
    __shared__ float sums[4][32];
    const int tid = threadIdx.x;
    const int i = blockIdx.x * 256 + tid;        // over BL*64
    float s = 0.0f;
#pragma unroll
    for (int ks = 0; ks < XKS; ++ks) s += part[(size_t)ks * (BL * 64) + i];
    xdbl[i] = s;
    const int col = i & 63;
    const int rowl = tid >> 6;                   // 4 rows per block
    if (col < 32) sums[rowl][col] = s;
    __syncthreads();

    const int row0 = blockIdx.x * 4;
#pragma unroll
    for (int k = 0; k < 6; ++k) {
        const int d = k * 256 + tid;
        const float b2 = 2.0f * b_dt[d];
        f32x4 w[8];
#pragma unroll
        for (int q = 0; q < 8; ++q) w[q] = *(const f32x4*)&W_dt[(size_t)d * 32 + q * 4];
        float acc0 = b2, acc1 = b2, acc2 = b2, acc3 = b2;
#pragma unroll
        for (int q = 0; q < 8; ++q) {
#pragma unroll
            for (int j = 0; j < 4; ++j) {
                const float wv = w[q][j];
                const int jj = q * 4 + j;
                acc0 += wv * sums[0][jj];
                acc1 += wv * sums[1][jj];
                acc2 += wv * sums[2][jj];
                acc3 += wv * sums[3][jj];
            }
        }
        dtgb[(size_t)(row0 + 0) * D_INNER + d] = f2bf(softplus_f(acc0));
        dtgb[(size_t)(row0 + 1) * D_INNER + d] = f2bf(softplus_f(acc1));
        dtgb[(size_t)(row0 + 2) * D_INNER + d] = f2bf(softplus_f(acc2));
        dtgb[(size_t)(row0 + 3) * D_INNER + d] = f2bf(softplus_f(acc3));
    }
}

// ---------------------------------------------------------------------------
// Depthwise causal conv (k=4) + bias + SiLU, 8 channels/thread (vectorized).
// ---------------------------------------------------------------------------
__global__ __launch_bounds__(256) void conv_silu_kernel(
    const unsigned short* __restrict__ xzb, const float* __restrict__ Wc,
    const float* __restrict__ bc, unsigned short* __restrict__ xcsb)
{
    const int i8 = blockIdx.x * 256 + threadIdx.x;   // over BL*D_INNER/8
    if (i8 >= BL * D_INNER / 8) return;
    const int dg = i8 % (D_INNER / 8);
    const int bl = i8 / (D_INNER / 8);
    const int l = bl % SEQ;
    const int d0 = dg * 8;
    const size_t rowb = (size_t)bl * E2 + d0;

    const u16x8 x0 = *(const u16x8*)&xzb[rowb];
    u16x8 x1 = {}, x2 = {}, x3 = {};
    if (l >= 1) x1 = *(const u16x8*)&xzb[rowb - E2];
    if (l >= 2) x2 = *(const u16x8*)&xzb[rowb - 2 * E2];
    if (l >= 3) x3 = *(const u16x8*)&xzb[rowb - 3 * E2];
    const f32x4 b0 = *(const f32x4*)&bc[d0];
    const f32x4 b1 = *(const f32x4*)&bc[d0 + 4];

    u16x8 o;
#pragma unroll
    for (int j = 0; j < 8; ++j) {
        const f32x4 w = *(const f32x4*)&Wc[(size_t)(d0 + j) * 4];
        float acc = (j < 4 ? b0[j] : b1[j - 4]);
        acc += w[3] * bf2f(x0[j]);
        acc += w[2] * bf2f(x1[j]);   // zero-init vectors make l<3 taps 0
        acc += w[1] * bf2f(x2[j]);
        acc += w[0] * bf2f(x3[j]);
        o[j] = f2bf(silu_f(acc));
    }
    *(u16x8*)&xcsb[(size_t)bl * D_INNER + d0] = o;
}

// ---------------------------------------------------------------------------
// 3-pass chunked selective scan.  Hc/Hinit stored bf16;
// scan_p2 uses a 4-deep statically-indexed software pipeline.
// ---------------------------------------------------------------------------
__global__ __launch_bounds__(256) void scan_p1(
    const unsigned short* __restrict__ dtgb, const unsigned short* __restrict__ xcsb,
    const float* __restrict__ xdbl, const float* __restrict__ A_log,
    unsigned short* __restrict__ Hc, float* __restrict__ sdt_arr)
{
    __shared__ unsigned short dt_s[TC][256];
    __shared__ unsigned short xc_s[TC][256];
    __shared__ float Bsh[TC][16];
    const int tid = threadIdx.x;
    const int d0 = blockIdx.x * 256;
    const int d = d0 + tid;
    const int c = blockIdx.y;
    const int b = blockIdx.z;
    const int r0 = b * SEQ + c * TC;

#pragma unroll
    for (int k = 0; k < TC * 32 / 256; ++k) {
        const int u = k * 256 + tid;
        const int t = u >> 5, c8 = (u & 31) * 8;
        *(u16x8*)&dt_s[t][c8] = *(const u16x8*)&dtgb[(size_t)(r0 + t) * D_INNER + d0 + c8];
        *(u16x8*)&xc_s[t][c8] = *(const u16x8*)&xcsb[(size_t)(r0 + t) * D_INNER + d0 + c8];
    }
    {
        const int t = tid >> 4, j = tid & 15;
        Bsh[t][j] = xdbl[(size_t)(r0 + t) * 64 + 32 + j];
    }
    float a[16];
#pragma unroll
    for (int q = 0; q < 4; ++q) {
        const f32x4 al = *(const f32x4*)&A_log[(size_t)d * 16 + q * 4];
#pragma unroll
        for (int j = 0; j < 4; ++j) a[q * 4 + j] = -__expf(al[j]);
    }
    __syncthreads();

    float h[16];
#pragma unroll
    for (int s = 0; s < 16; ++s) h[s] = 0.0f;
    float sdt = 0.0f;
#pragma unroll
    for (int t = 0; t < TC; ++t) {
        const float dt = bf2f(dt_s[t][tid]);
        const float xc = bf2f(xc_s[t][tid]);
        sdt += dt;
        const float u = dt * xc;
        const f32x4 B0 = *(const f32x4*)&Bsh[t][0];
        const f32x4 B1 = *(const f32x4*)&Bsh[t][4];
        const f32x4 B2 = *(const f32x4*)&Bsh[t][8];
        const f32x4 B3 = *(const f32x4*)&Bsh[t][12];
#pragma unroll
        for (int s = 0; s < 16; ++s) {
            const float Bv = (s < 4 ? B0[s] : s < 8 ? B1[s - 4] : s < 12 ? B2[s - 8] : B3[s - 12]);
            h[s] = __expf(dt * a[s]) * h[s] + u * Bv;
        }
    }
    const size_t o = (((size_t)b * NCHUNK + c) * D_INNER + d) * 16;
    u16x8 h0, h1;
#pragma unroll
    for (int j = 0; j < 8; ++j) { h0[j] = f2bf(h[j]); h1[j] = f2bf(h[8 + j]); }
    *(u16x8*)&Hc[o] = h0;
    *(u16x8*)&Hc[o + 8] = h1;
    sdt_arr[((size_t)b * NCHUNK + c) * D_INNER + d] = sdt;
}

// 4-deep software-pipelined chunk combine (bf16 state).
__global__ __launch_bounds__(256) void scan_p2(
    unsigned short* __restrict__ Hc, const float* __restrict__ sdt_arr,
    const float* __restrict__ A_log)
{
    const int idx = blockIdx.x * 256 + threadIdx.x;
    if (idx >= BATCH * D_INNER * 16) return;
    const int b = idx / (D_INNER * 16);
    const int ds = idx % (D_INNER * 16);
    const int d = ds >> 4;
    const float a = -__expf(A_log[ds]);
    const size_t hstep = (size_t)D_INNER * 16;
    const size_t sstep = (size_t)D_INNER;
    size_t oh = (size_t)b * NCHUNK * hstep + ds;
    size_t os = (size_t)b * NCHUNK * sstep + d;

    // 4 named pipeline slots (static indexing only — rule #20)
    float hc0 = bf2f(Hc[oh]);             float sd0 = sdt_arr[os];
    float hc1 = bf2f(Hc[oh + hstep]);     float sd1 = sdt_arr[os + sstep];
    float hc2 = bf2f(Hc[oh + 2 * hstep]); float sd2 = sdt_arr[os + 2 * sstep];
    float hc3 = bf2f(Hc[oh + 3 * hstep]); float sd3 = sdt_arr[os + 3 * sstep];
    float h = 0.0f;

#pragma unroll
    for (int c = 0; c < NCHUNK; c += 4) {
        {
            const float E = __expf(sd0 * a);
            Hc[oh] = f2bf(h);
            h = E * h + hc0;
            if (c + 4 < NCHUNK) { hc0 = bf2f(Hc[oh + 4 * hstep]); sd0 = sdt_arr[os + 4 * sstep]; }
            oh += hstep; os += sstep;
        }
        {
            const float E = __expf(sd1 * a);
            Hc[oh] = f2bf(h);
            h = E * h + hc1;
            if (c + 5 < NCHUNK) { hc1 = bf2f(Hc[oh + 4 * hstep]); sd1 = sdt_arr[os + 4 * sstep]; }
            oh += hstep; os += sstep;
        }
        {
            const float E = __expf(sd2 * a);
            Hc[oh] = f2bf(h);
            h = E * h + hc2;
            if (c + 6 < NCHUNK) { hc2 = bf2f(Hc[oh + 4 * hstep]); sd2 = sdt_arr[os + 4 * sstep]; }
            oh += hstep; os += sstep;
        }
        {
            const float E = __expf(sd3 * a);
            Hc[oh] = f2bf(h);
            h = E * h + hc3;
            if (c + 7 < NCHUNK) { hc3 = bf2f(Hc[oh + 4 * hstep]); sd3 = sdt_arr[os + 4 * sstep]; }
            oh += hstep; os += sstep;
        }
    }
}

__global__ __launch_bounds__(256) void scan_p3(
    const unsigned short* __restrict__ dtgb, const unsigned short* __restrict__ xcsb,
    const float* __restrict__ xdbl, const float* __restrict__ A_log,
    const float* __restrict__ Dp, const unsigned short* __restrict__ Hinit,
    const unsigned short* __restrict__ xzb, unsigned short* __restrict__ ymb)
{
    __shared__ unsigned short dt_s[TC][256];
    __shared__ unsigned short xc_s[TC][256];
    __shared__ unsigned short z_s[TC][256];
    __shared__ float BCsh[TC][32];
    const int tid = threadIdx.x;
    const int d0 = blockIdx.x * 256;
    const int d = d0 + tid;
    const int c = blockIdx.y;
    const int b = blockIdx.z;
    const int r0 = b * SEQ + c * TC;

#pragma unroll
    for (int k = 0; k < TC * 32 / 256; ++k) {
        const int u = k * 256 + tid;
        const int t = u >> 5, c8 = (u & 31) * 8;
        *(u16x8*)&dt_s[t][c8] = *(const u16x8*)&dtgb[(size_t)(r0 + t) * D_INNER + d0 + c8];
        *(u16x8*)&xc_s[t][c8] = *(const u16x8*)&xcsb[(size_t)(r0 + t) * D_INNER + d0 + c8];
        *(u16x8*)&z_s[t][c8]  = *(const u16x8*)&xzb[(size_t)(r0 + t) * E2 + D_INNER + d0 + c8];
    }
    for (int i = tid; i < TC * 32; i += 256) {
        const int t = i >> 5, j = i & 31;
        BCsh[t][j] = xdbl[(size_t)(r0 + t) * 64 + 32 + j];
    }
    float a[16];
#pragma unroll
    for (int q = 0; q < 4; ++q) {
        const f32x4 al = *(const f32x4*)&A_log[(size_t)d * 16 + q * 4];
#pragma unroll
        for (int j = 0; j < 4; ++j) a[q * 4 + j] = -__expf(al[j]);
    }
    const float Dd = Dp[d];
    float h[16];
    {
        const size_t o = (((size_t)b * NCHUNK + c) * D_INNER + d) * 16;
        const u16x8 h0 = *(const u16x8*)&Hinit[o];
        const u16x8 h1 = *(const u16x8*)&Hinit[o + 8];
#pragma unroll
        for (int j = 0; j < 8; ++j) { h[j] = bf2f(h0[j]); h[8 + j] = bf2f(h1[j]); }
    }
    __syncthreads();

    const size_t base = (size_t)r0 * D_INNER + d;
#pragma unroll
    for (int t = 0; t < TC; ++t) {
        const float dt = bf2f(dt_s[t][tid]);
        const float xc = bf2f(xc_s[t][tid]);
        const float z  = bf2f(z_s[t][tid]);
        const float u = dt * xc;
        const f32x4 B0 = *(const f32x4*)&BCsh[t][0];
        const f32x4 B1 = *(const f32x4*)&BCsh[t][4];
        const f32x4 B2 = *(const f32x4*)&BCsh[t][8];
        const f32x4 B3 = *(const f32x4*)&BCsh[t][12];
        const f32x4 C0 = *(const f32x4*)&BCsh[t][16];
        const f32x4 C1 = *(const f32x4*)&BCsh[t][20];
        const f32x4 C2 = *(const f32x4*)&BCsh[t][24];
        const f32x4 C3 = *(const f32x4*)&BCsh[t][28];
        float y = 0.0f;
#pragma unroll
        for (int s = 0; s < 16; ++s) {
            const float Bv = (s < 4 ? B0[s] : s < 8 ? B1[s - 4] : s < 12 ? B2[s - 8] : B3[s - 12]);
            const float Cv = (s < 4 ? C0[s] : s < 8 ? C1[s - 4] : s < 12 ? C2[s - 8] : C3[s - 12]);
            h[s] = __expf(dt * a[s]) * h[s] + u * Bv;
            y += h[s] * Cv;
        }
        y += xc * Dd;
        ymb[base + (size_t)t * D_INNER] = f2bf(y * silu_f(z));
    }
}

extern "C" void kernel_launch(void* const* d_in, const int* in_sizes, int n_in,
                              void* d_out, int out_size, void* d_ws, size_t ws_size,
                              hipStream_t stream) {
    const float* x      = (const float*)d_in[0];
    const float* W_in   = (const float*)d_in[1];
    const float* W_conv = (const float*)d_in[2];
    const float* b_conv = (const float*)d_in[3];
    const float* W_x    = (const float*)d_in[4];
    const float* W_dt   = (const float*)d_in[5];
    const float* b_dt   = (const float*)d_in[6];
    const float* A_log  = (const float*)d_in[7];
    const float* Dp     = (const float*)d_in[8];
    const float* W_out  = (const float*)d_in[9];
    float* out = (float*)d_out;

    // linear workspace layout (all bf16 intermediates)
    char* p = (char*)d_ws;
    auto alloc = [&](size_t bytes) { char* r = p; p += (bytes + 255) & ~(size_t)255; return r; };
    unsigned short* xzb     = (unsigned short*)alloc((size_t)BL * E2 * 2);
    unsigned short* xcsb    = (unsigned short*)alloc((size_t)BL * D_INNER * 2);
    unsigned short* dtgb    = (unsigned short*)alloc((size_t)BL * D_INNER * 2);
    unsigned short* ymb     = (unsigned short*)alloc((size_t)BL * D_INNER * 2);
    unsigned short* xb      = (unsigned short*)alloc((size_t)BL * DIM * 2);
    unsigned short* W_in_b  = (unsigned short*)alloc((size_t)E2 * DIM * 2);
    unsigned short* W_out_b = (unsigned short*)alloc((size_t)DIM * D_INNER * 2);
    unsigned short* W_x_b   = (unsigned short*)alloc((size_t)64 * D_INNER * 2);
    float* xdbl             = (float*)alloc((size_t)BL * 64 * 4);
    float* part             = (float*)alloc((size_t)XKS * BL * 64 * 4);
    unsigned short* Hc      = (unsigned short*)alloc((size_t)BATCH * NCHUNK * D_INNER * 16 * 2);
    float* sdt              = (float*)alloc((size_t)BATCH * NCHUNK * D_INNER * 4);

    // 0. f32->bf16 conversions (W_in, x, W_out, W_x) in one dispatch
    cvt4_kernel<<<(294912 + 196608 + 147456 + 12288) / 256, 256, 0, stream>>>(
        W_in, W_in_b, E2 * DIM / 8,
        x, xb, BL * DIM / 8,
        W_out, W_out_b, DIM * D_INNER / 8,
        W_x, W_x_b, 64 * D_INNER / 8);
    // 1. xz = x @ W_in^T  (bf16 MFMA -> bf16, 128x128 tiles, 2D grid)
    gemm_bf16<128, 128, 3><<<dim3(E2 / 128, BL / 128), 256, 0, stream>>>(
        xb, W_in_b, xzb, E2, nullptr, 0, DIM);
    // 2. depthwise causal conv + bias + silu (bf16 in/out, 8 ch/thread)
    conv_silu_kernel<<<(BL * D_INNER / 8) / 256, 256, 0, stream>>>(
        xzb, W_conv, b_conv, xcsb);
    // 3. x_dbl split-K MFMA GEMM; fused reduce + dt projection
    xdbl_gemm<<<dim3(XKS, BL / 128), 256, 0, stream>>>(xcsb, W_x_b, part);
    xdbl_reduce_dt<<<(BL * 64) / 256, 256, 0, stream>>>(
        part, xdbl, W_dt, b_dt, dtgb);
    // 4. 3-pass chunked selective scan (bf16 state, pipelined combine)
    scan_p1<<<dim3(D_INNER / 256, NCHUNK, BATCH), 256, 0, stream>>>(
        dtgb, xcsb, xdbl, A_log, Hc, sdt);
    scan_p2<<<(BATCH * D_INNER * 16) / 256, 256, 0, stream>>>(Hc, sdt, A_log);
    scan_p3<<<dim3(D_INNER / 256, NCHUNK, BATCH), 256, 0, stream>>>(
        dtgb, xcsb, xdbl, A_log, Dp, Hc, xzb, ymb);
    // 5. out = ym @ W_out^T + x  (bf16 MFMA, 64x64 tiles, 2D grid)
    gemm_bf16<64, 64, 2><<<dim3(DIM / 64, BL / 64), 256, 0, stream>>>(
        ymb, W_out_b, out, DIM, x, DIM, D_INNER);
}

// Round 17
// 108.230 us; speedup vs baseline: 1.1829x; 1.1829x over previous
//
#include <hip/hip_runtime.h>
#include <stdint.h>

#define DIM 768
#define D_STATE 16
#define D_CONV 4
#define DT_RANK 32
#define D_INNER 1536
#define BATCH 2
#define SEQ 1024
#define BL (BATCH * SEQ)   // 2048
#define E2 (2 * D_INNER)   // 3072
#define NCHUNK 64
#define TC (SEQ / NCHUNK)  // 16 steps per chunk
#define XKS 8              // split-K factor for x_dbl GEMM
#define XKC (D_INNER / XKS) // 192

typedef __attribute__((ext_vector_type(8))) __bf16 bf16x8;
typedef __attribute__((ext_vector_type(4))) float f32x4;
typedef __attribute__((ext_vector_type(8))) unsigned short u16x8;

__device__ __forceinline__ float silu_f(float v) {
    return v / (1.0f + __expf(-v));
}
// fast softplus: hardware exp/log path
__device__ __forceinline__ float softplus_f(float v) {
    return fmaxf(v, 0.0f) + __logf(1.0f + __expf(-fabsf(v)));
}
__device__ __forceinline__ unsigned short f2bf(float f) {
    uint32_t u = __float_as_uint(f);
    u += 0x7FFFu + ((u >> 16) & 1u);          // round-to-nearest-even
    return (unsigned short)(u >> 16);
}
__device__ __forceinline__ float bf2f(unsigned short u) {
    return __uint_as_float((uint32_t)u << 16);
}
// global -> LDS direct copy, 16B per lane. LDS dest: wave-uniform base + lane*16.
__device__ __forceinline__ void gload_lds16(const void* g, void* l) {
    __builtin_amdgcn_global_load_lds(
        (const __attribute__((address_space(1))) unsigned int*)(uintptr_t)g,
        (__attribute__((address_space(3))) unsigned int*)(uint32_t)(uintptr_t)l,
        16, 0, 0);
}

// ---------------------------------------------------------------------------
// Fused f32->bf16 conversion: W_in, x, W_out, W_x, W_dt in one dispatch.
// ---------------------------------------------------------------------------
__global__ __launch_bounds__(256) void cvt5_kernel(
    const float* __restrict__ s0, unsigned short* __restrict__ d0, int n0,
    const float* __restrict__ s1, unsigned short* __restrict__ d1, int n1,
    const float* __restrict__ s2, unsigned short* __restrict__ d2, int n2,
    const float* __restrict__ s3, unsigned short* __restrict__ d3, int n3,
    const float* __restrict__ s4, unsigned short* __restrict__ d4, int n4)
{
    int i = blockIdx.x * 256 + threadIdx.x;
    const float* s; unsigned short* d;
    if (i < n0)                          { s = s0; d = d0; }
    else if ((i -= n0) < n1)             { s = s1; d = d1; }
    else if ((i -= n1) < n2)             { s = s2; d = d2; }
    else if ((i -= n2) < n3)             { s = s3; d = d3; }
    else { i -= n3; if (i >= n4) return;   s = s4; d = d4; }
    const f32x4 a = ((const f32x4*)s)[2 * i];
    const f32x4 b = ((const f32x4*)s)[2 * i + 1];
    u16x8 o;
#pragma unroll
    for (int j = 0; j < 4; ++j) { o[j] = f2bf(a[j]); o[4 + j] = f2bf(b[j]); }
    ((u16x8*)d)[i] = o;
}

// ---------------------------------------------------------------------------
// bf16 MFMA GEMM, templated tile: C[M,N] = A[M,K]bf16 * B[N,K]^T bf16.
// 4 waves (2x2), 16x16x32 MFMA, 2-phase double-buffered LDS.
// EPI 0: f32 out.  EPI 1: softplus(acc+2*X[col]) -> bf16 out.
// EPI 2: acc + X[row*ldx+col] -> f32 out.  EPI 3: bf16 out.
// ---------------------------------------------------------------------------
template <int BM, int BN, int EPI>
__global__ __launch_bounds__(256) void gemm_bf16(
    const unsigned short* __restrict__ A, const unsigned short* __restrict__ B,
    void* __restrict__ C, int ldc,
    const float* __restrict__ X, int ldx, int K)
{
    constexpr int NROW = BM + BN;      // staged rows (A then B), 32 bf16 cols
    constexpr int RW = NROW / 4;       // rows per wave
    constexpr int NC = RW / 16;        // gload_lds16 calls per wave per tile
    constexpr int FM = BM / 32;        // frag rows per wave (2x2 wave grid)
    constexpr int FN = BN / 32;
    __shared__ __align__(16) unsigned short S[2][NROW * 32];
    const int tid = threadIdx.x;
    const int wid = tid >> 6;
    const int lane = tid & 63;
    const int wr = wid >> 1, wc = wid & 1;
    const int bm = blockIdx.y * BM, bn = blockIdx.x * BN;

    const int lrow = lane >> 2;
    const int scol = (lane & 3) * 8;
    const unsigned short* gsrc[NC];
#pragma unroll
    for (int c = 0; c < NC; ++c) {
        const int rowbase = wid * RW + c * 16;       // wave-uniform, %16==0
        const int grow = rowbase + lrow;
        gsrc[c] = (rowbase < BM)
            ? A + (size_t)(bm + grow) * K + scol
            : B + (size_t)(bn + grow - BM) * K + scol;
    }

    const int fr = lane & 15;
    const int fq = lane >> 4;
    f32x4 acc[FM][FN] = {};

    auto STAGE = [&](int nb, int k0) {
#pragma unroll
        for (int c = 0; c < NC; ++c)
            gload_lds16(gsrc[c] + k0, &S[nb][(wid * RW + c * 16) * 32]);
    };
    auto COMPUTE = [&](int cb) {
        bf16x8 af[FM], bfr[FN];
#pragma unroll
        for (int m = 0; m < FM; ++m)
            af[m] = *(const bf16x8*)&S[cb][(wr * (BM / 2) + m * 16 + fr) * 32 + fq * 8];
#pragma unroll
        for (int n = 0; n < FN; ++n)
            bfr[n] = *(const bf16x8*)&S[cb][(BM + wc * (BN / 2) + n * 16 + fr) * 32 + fq * 8];
#pragma unroll
        for (int m = 0; m < FM; ++m)
#pragma unroll
            for (int n = 0; n < FN; ++n)
                acc[m][n] = __builtin_amdgcn_mfma_f32_16x16x32_bf16(
                    af[m], bfr[n], acc[m][n], 0, 0, 0);
    };

    STAGE(0, 0);
    asm volatile("s_waitcnt vmcnt(0)" ::: "memory");
    __builtin_amdgcn_s_barrier();
    int cur = 0;
    for (int k0 = 32; k0 < K; k0 += 32) {
        STAGE(cur ^ 1, k0);      // next tile's loads fly under compute
        COMPUTE(cur);
        asm volatile("s_waitcnt vmcnt(0)" ::: "memory");
        __builtin_amdgcn_s_barrier();
        cur ^= 1;
    }
    COMPUTE(cur);

#pragma unroll
    for (int m = 0; m < FM; ++m) {
#pragma unroll
        for (int n = 0; n < FN; ++n) {
            const int col = bn + wc * (BN / 2) + n * 16 + fr;
#pragma unroll
            for (int r = 0; r < 4; ++r) {
                const int row = bm + wr * (BM / 2) + m * 16 + fq * 4 + r;
                float o = acc[m][n][r];
                if (EPI == 0) {
                    ((float*)C)[(size_t)row * ldc + col] = o;
                } else if (EPI == 1) {
                    o = softplus_f(o + 2.0f * X[col]);
                    ((unsigned short*)C)[(size_t)row * ldc + col] = f2bf(o);
                } else if (EPI == 2) {
                    o += X[(size_t)row * ldx + col];
                    ((float*)C)[(size_t)row * ldc + col] = o;
                } else {
                    ((unsigned short*)C)[(size_t)row * ldc + col] = f2bf(o);
                }
            }
        }
    }
}

// ---------------------------------------------------------------------------
// x_dbl GEMM, split-K: part[ks][M][64] = xcsb[M, ks*192:+192] @ W_x^T chunk.
// ---------------------------------------------------------------------------
__global__ __launch_bounds__(256) void xdbl_gemm(
    const unsigned short* __restrict__ xcsb,
    const unsigned short* __restrict__ W_x_b,
    float* __restrict__ part)
{
    constexpr int BM = 128, NROW = BM + 64, RW = NROW / 4, NC = RW / 16;
    __shared__ __align__(16) unsigned short S[2][NROW * 32];
    const int tid = threadIdx.x;
    const int wid = tid >> 6, lane = tid & 63;
    const int wr = wid >> 1, wc = wid & 1;
    const int bm = blockIdx.y * BM;
    const int kb = blockIdx.x * XKC;
    const int lrow = lane >> 2, scol = (lane & 3) * 8;
    const unsigned short* gsrc[NC];
#pragma unroll
    for (int c = 0; c < NC; ++c) {
        const int rowbase = wid * RW + c * 16;
        const int grow = rowbase + lrow;
        gsrc[c] = (rowbase < BM)
            ? xcsb + (size_t)(bm + grow) * D_INNER + kb + scol
            : W_x_b + (size_t)(grow - BM) * D_INNER + kb + scol;
    }
    const int fr = lane & 15, fq = lane >> 4;
    f32x4 acc[4][2] = {};
    auto STAGE = [&](int nb, int k0) {
#pragma unroll
        for (int c = 0; c < NC; ++c)
            gload_lds16(gsrc[c] + k0, &S[nb][(wid * RW + c * 16) * 32]);
    };
    auto COMPUTE = [&](int cb) {
        bf16x8 af[4], bfr[2];
#pragma unroll
        for (int m = 0; m < 4; ++m)
            af[m] = *(const bf16x8*)&S[cb][(wr * 64 + m * 16 + fr) * 32 + fq * 8];
#pragma unroll
        for (int n = 0; n < 2; ++n)
            bfr[n] = *(const bf16x8*)&S[cb][(BM + wc * 32 + n * 16 + fr) * 32 + fq * 8];
#pragma unroll
        for (int m = 0; m < 4; ++m)
#pragma unroll
            for (int n = 0; n < 2; ++n)
                acc[m][n] = __builtin_amdgcn_mfma_f32_16x16x32_bf16(
                    af[m], bfr[n], acc[m][n], 0, 0, 0);
    };
    STAGE(0, 0);
    asm volatile("s_waitcnt vmcnt(0)" ::: "memory");
    __builtin_amdgcn_s_barrier();
    int cur = 0;
    for (int k0 = 32; k0 < XKC; k0 += 32) {
        STAGE(cur ^ 1, k0);
        COMPUTE(cur);
        asm volatile("s_waitcnt vmcnt(0)" ::: "memory");
        __builtin_amdgcn_s_barrier();
        cur ^= 1;
    }
    COMPUTE(cur);
    float* P = part + (size_t)blockIdx.x * BL * 64;
#pragma unroll
    for (int m = 0; m < 4; ++m)
#pragma unroll
        for (int n = 0; n < 2; ++n) {
            const int col = wc * 32 + n * 16 + fr;
#pragma unroll
            for (int r = 0; r < 4; ++r) {
                const int row = bm + wr * 64 + m * 16 + fq * 4 + r;
                P[(size_t)row * 64 + col] = acc[m][n][r];
            }
        }
}

// ---------------------------------------------------------------------------
// Reduce split-K partials -> xdbl fp32 (B,C for scan) + dt_lr bf16 rows.
// ---------------------------------------------------------------------------
__global__ __launch_bounds__(256) void xdbl_reduce(
    const float* __restrict__ part, float* __restrict__ xdbl,
    unsigned short* __restrict__ dtlrb)
{
    const int i = blockIdx.x * 256 + threadIdx.x;   // over BL*64
    if (i >= BL * 64) return;
    float s = 0.0f;
#pragma unroll
    for (int ks = 0; ks < XKS; ++ks) s += part[(size_t)ks * (BL * 64) + i];
    xdbl[i] = s;
    const int col = i & 63, row = i >> 6;
    if (col < 32) dtlrb[row * 32 + col] = f2bf(s);
}

// ---------------------------------------------------------------------------
// Depthwise causal conv (k=4) + bias + SiLU, 8 channels/thread (vectorized).
// ---------------------------------------------------------------------------
__global__ __launch_bounds__(256) void conv_silu_kernel(
    const unsigned short* __restrict__ xzb, const float* __restrict__ Wc,
    const float* __restrict__ bc, unsigned short* __restrict__ xcsb)
{
    const int i8 = blockIdx.x * 256 + threadIdx.x;   // over BL*D_INNER/8
    if (i8 >= BL * D_INNER / 8) return;
    const int dg = i8 % (D_INNER / 8);
    const int bl = i8 / (D_INNER / 8);
    const int l = bl % SEQ;
    const int d0 = dg * 8;
    const size_t rowb = (size_t)bl * E2 + d0;

    const u16x8 x0 = *(const u16x8*)&xzb[rowb];
    u16x8 x1 = {}, x2 = {}, x3 = {};
    if (l >= 1) x1 = *(const u16x8*)&xzb[rowb - E2];
    if (l >= 2) x2 = *(const u16x8*)&xzb[rowb - 2 * E2];
    if (l >= 3) x3 = *(const u16x8*)&xzb[rowb - 3 * E2];
    const f32x4 b0 = *(const f32x4*)&bc[d0];
    const f32x4 b1 = *(const f32x4*)&bc[d0 + 4];

    u16x8 o;
#pragma unroll
    for (int j = 0; j < 8; ++j) {
        const f32x4 w = *(const f32x4*)&Wc[(size_t)(d0 + j) * 4];
        float acc = (j < 4 ? b0[j] : b1[j - 4]);
        acc += w[3] * bf2f(x0[j]);
        acc += w[2] * bf2f(x1[j]);   // zero-init vectors make l<3 taps 0
        acc += w[1] * bf2f(x2[j]);
        acc += w[0] * bf2f(x3[j]);
        o[j] = f2bf(silu_f(acc));
    }
    *(u16x8*)&xcsb[(size_t)bl * D_INNER + d0] = o;
}

// ---------------------------------------------------------------------------
// 3-pass chunked selective scan.  Hc/Hinit stored bf16;
// scan_p2 uses a 4-deep statically-indexed software pipeline.
// ---------------------------------------------------------------------------
__global__ __launch_bounds__(256) void scan_p1(
    const unsigned short* __restrict__ dtgb, const unsigned short* __restrict__ xcsb,
    const float* __restrict__ xdbl, const float* __restrict__ A_log,
    unsigned short* __restrict__ Hc, float* __restrict__ sdt_arr)
{
    __shared__ unsigned short dt_s[TC][256];
    __shared__ unsigned short xc_s[TC][256];
    __shared__ float Bsh[TC][16];
    const int tid = threadIdx.x;
    const int d0 = blockIdx.x * 256;
    const int d = d0 + tid;
    const int c = blockIdx.y;
    const int b = blockIdx.z;
    const int r0 = b * SEQ + c * TC;

#pragma unroll
    for (int k = 0; k < TC * 32 / 256; ++k) {
        const int u = k * 256 + tid;
        const int t = u >> 5, c8 = (u & 31) * 8;
        *(u16x8*)&dt_s[t][c8] = *(const u16x8*)&dtgb[(size_t)(r0 + t) * D_INNER + d0 + c8];
        *(u16x8*)&xc_s[t][c8] = *(const u16x8*)&xcsb[(size_t)(r0 + t) * D_INNER + d0 + c8];
    }
    {
        const int t = tid >> 4, j = tid & 15;
        Bsh[t][j] = xdbl[(size_t)(r0 + t) * 64 + 32 + j];
    }
    float a[16];
#pragma unroll
    for (int q = 0; q < 4; ++q) {
        const f32x4 al = *(const f32x4*)&A_log[(size_t)d * 16 + q * 4];
#pragma unroll
        for (int j = 0; j < 4; ++j) a[q * 4 + j] = -__expf(al[j]);
    }
    __syncthreads();

    float h[16];
#pragma unroll
    for (int s = 0; s < 16; ++s) h[s] = 0.0f;
    float sdt = 0.0f;
#pragma unroll
    for (int t = 0; t < TC; ++t) {
        const float dt = bf2f(dt_s[t][tid]);
        const float xc = bf2f(xc_s[t][tid]);
        sdt += dt;
        const float u = dt * xc;
        const f32x4 B0 = *(const f32x4*)&Bsh[t][0];
        const f32x4 B1 = *(const f32x4*)&Bsh[t][4];
        const f32x4 B2 = *(const f32x4*)&Bsh[t][8];
        const f32x4 B3 = *(const f32x4*)&Bsh[t][12];
#pragma unroll
        for (int s = 0; s < 16; ++s) {
            const float Bv = (s < 4 ? B0[s] : s < 8 ? B1[s - 4] : s < 12 ? B2[s - 8] : B3[s - 12]);
            h[s] = __expf(dt * a[s]) * h[s] + u * Bv;
        }
    }
    const size_t o = (((size_t)b * NCHUNK + c) * D_INNER + d) * 16;
    u16x8 h0, h1;
#pragma unroll
    for (int j = 0; j < 8; ++j) { h0[j] = f2bf(h[j]); h1[j] = f2bf(h[8 + j]); }
    *(u16x8*)&Hc[o] = h0;
    *(u16x8*)&Hc[o + 8] = h1;
    sdt_arr[((size_t)b * NCHUNK + c) * D_INNER + d] = sdt;
}

// 4-deep software-pipelined chunk combine (bf16 state).
__global__ __launch_bounds__(256) void scan_p2(
    unsigned short* __restrict__ Hc, const float* __restrict__ sdt_arr,
    const float* __restrict__ A_log)
{
    const int idx = blockIdx.x * 256 + threadIdx.x;
    if (idx >= BATCH * D_INNER * 16) return;
    const int b = idx / (D_INNER * 16);
    const int ds = idx % (D_INNER * 16);
    const int d = ds >> 4;
    const float a = -__expf(A_log[ds]);
    const size_t hstep = (size_t)D_INNER * 16;
    const size_t sstep = (size_t)D_INNER;
    size_t oh = (size_t)b * NCHUNK * hstep + ds;
    size_t os = (size_t)b * NCHUNK * sstep + d;

    // 4 named pipeline slots (static indexing only — rule #20)
    float hc0 = bf2f(Hc[oh]);             float sd0 = sdt_arr[os];
    float hc1 = bf2f(Hc[oh + hstep]);     float sd1 = sdt_arr[os + sstep];
    float hc2 = bf2f(Hc[oh + 2 * hstep]); float sd2 = sdt_arr[os + 2 * sstep];
    float hc3 = bf2f(Hc[oh + 3 * hstep]); float sd3 = sdt_arr[os + 3 * sstep];
    float h = 0.0f;

#pragma unroll
    for (int c = 0; c < NCHUNK; c += 4) {
        {
            const float E = __expf(sd0 * a);
            Hc[oh] = f2bf(h);
            h = E * h + hc0;
            if (c + 4 < NCHUNK) { hc0 = bf2f(Hc[oh + 4 * hstep]); sd0 = sdt_arr[os + 4 * sstep]; }
            oh += hstep; os += sstep;
        }
        {
            const float E = __expf(sd1 * a);
            Hc[oh] = f2bf(h);
            h = E * h + hc1;
            if (c + 5 < NCHUNK) { hc1 = bf2f(Hc[oh + 4 * hstep]); sd1 = sdt_arr[os + 4 * sstep]; }
            oh += hstep; os += sstep;
        }
        {
            const float E = __expf(sd2 * a);
            Hc[oh] = f2bf(h);
            h = E * h + hc2;
            if (c + 6 < NCHUNK) { hc2 = bf2f(Hc[oh + 4 * hstep]); sd2 = sdt_arr[os + 4 * sstep]; }
            oh += hstep; os += sstep;
        }
        {
            const float E = __expf(sd3 * a);
            Hc[oh] = f2bf(h);
            h = E * h + hc3;
            if (c + 7 < NCHUNK) { hc3 = bf2f(Hc[oh + 4 * hstep]); sd3 = sdt_arr[os + 4 * sstep]; }
            oh += hstep; os += sstep;
        }
    }
}

__global__ __launch_bounds__(256) void scan_p3(
    const unsigned short* __restrict__ dtgb, const unsigned short* __restrict__ xcsb,
    const float* __restrict__ xdbl, const float* __restrict__ A_log,
    const float* __restrict__ Dp, const unsigned short* __restrict__ Hinit,
    const unsigned short* __restrict__ xzb, unsigned short* __restrict__ ymb)
{
    __shared__ unsigned short dt_s[TC][256];
    __shared__ unsigned short xc_s[TC][256];
    __shared__ unsigned short z_s[TC][256];
    __shared__ float BCsh[TC][32];
    const int tid = threadIdx.x;
    const int d0 = blockIdx.x * 256;
    const int d = d0 + tid;
    const int c = blockIdx.y;
    const int b = blockIdx.z;
    const int r0 = b * SEQ + c * TC;

#pragma unroll
    for (int k = 0; k < TC * 32 / 256; ++k) {
        const int u = k * 256 + tid;
        const int t = u >> 5, c8 = (u & 31) * 8;
        *(u16x8*)&dt_s[t][c8] = *(const u16x8*)&dtgb[(size_t)(r0 + t) * D_INNER + d0 + c8];
        *(u16x8*)&xc_s[t][c8] = *(const u16x8*)&xcsb[(size_t)(r0 + t) * D_INNER + d0 + c8];
        *(u16x8*)&z_s[t][c8]  = *(const u16x8*)&xzb[(size_t)(r0 + t) * E2 + D_INNER + d0 + c8];
    }
    for (int i = tid; i < TC * 32; i += 256) {
        const int t = i >> 5, j = i & 31;
        BCsh[t][j] = xdbl[(size_t)(r0 + t) * 64 + 32 + j];
    }
    float a[16];
#pragma unroll
    for (int q = 0; q < 4; ++q) {
        const f32x4 al = *(const f32x4*)&A_log[(size_t)d * 16 + q * 4];
#pragma unroll
        for (int j = 0; j < 4; ++j) a[q * 4 + j] = -__expf(al[j]);
    }
    const float Dd = Dp[d];
    float h[16];
    {
        const size_t o = (((size_t)b * NCHUNK + c) * D_INNER + d) * 16;
        const u16x8 h0 = *(const u16x8*)&Hinit[o];
        const u16x8 h1 = *(const u16x8*)&Hinit[o + 8];
#pragma unroll
        for (int j = 0; j < 8; ++j) { h[j] = bf2f(h0[j]); h[8 + j] = bf2f(h1[j]); }
    }
    __syncthreads();

    const size_t base = (size_t)r0 * D_INNER + d;
#pragma unroll
    for (int t = 0; t < TC; ++t) {
        const float dt = bf2f(dt_s[t][tid]);
        const float xc = bf2f(xc_s[t][tid]);
        const float z  = bf2f(z_s[t][tid]);
        const float u = dt * xc;
        const f32x4 B0 = *(const f32x4*)&BCsh[t][0];
        const f32x4 B1 = *(const f32x4*)&BCsh[t][4];
        const f32x4 B2 = *(const f32x4*)&BCsh[t][8];
        const f32x4 B3 = *(const f32x4*)&BCsh[t][12];
        const f32x4 C0 = *(const f32x4*)&BCsh[t][16];
        const f32x4 C1 = *(const f32x4*)&BCsh[t][20];
        const f32x4 C2 = *(const f32x4*)&BCsh[t][24];
        const f32x4 C3 = *(const f32x4*)&BCsh[t][28];
        float y = 0.0f;
#pragma unroll
        for (int s = 0; s < 16; ++s) {
            const float Bv = (s < 4 ? B0[s] : s < 8 ? B1[s - 4] : s < 12 ? B2[s - 8] : B3[s - 12]);
            const float Cv = (s < 4 ? C0[s] : s < 8 ? C1[s - 4] : s < 12 ? C2[s - 8] : C3[s - 12]);
            h[s] = __expf(dt * a[s]) * h[s] + u * Bv;
            y += h[s] * Cv;
        }
        y += xc * Dd;
        ymb[base + (size_t)t * D_INNER] = f2bf(y * silu_f(z));
    }
}

extern "C" void kernel_launch(void* const* d_in, const int* in_sizes, int n_in,
                              void* d_out, int out_size, void* d_ws, size_t ws_size,
                              hipStream_t stream) {
    const float* x      = (const float*)d_in[0];
    const float* W_in   = (const float*)d_in[1];
    const float* W_conv = (const float*)d_in[2];
    const float* b_conv = (const float*)d_in[3];
    const float* W_x    = (const float*)d_in[4];
    const float* W_dt   = (const float*)d_in[5];
    const float* b_dt   = (const float*)d_in[6];
    const float* A_log  = (const float*)d_in[7];
    const float* Dp     = (const float*)d_in[8];
    const float* W_out  = (const float*)d_in[9];
    float* out = (float*)d_out;

    // linear workspace layout (all bf16 intermediates)
    char* p = (char*)d_ws;
    auto alloc = [&](size_t bytes) { char* r = p; p += (bytes + 255) & ~(size_t)255; return r; };
    unsigned short* xzb     = (unsigned short*)alloc((size_t)BL * E2 * 2);
    unsigned short* xcsb    = (unsigned short*)alloc((size_t)BL * D_INNER * 2);
    unsigned short* dtgb    = (unsigned short*)alloc((size_t)BL * D_INNER * 2);
    unsigned short* ymb     = (unsigned short*)alloc((size_t)BL * D_INNER * 2);
    unsigned short* dtlrb   = (unsigned short*)alloc((size_t)BL * 32 * 2);
    unsigned short* xb      = (unsigned short*)alloc((size_t)BL * DIM * 2);
    unsigned short* W_in_b  = (unsigned short*)alloc((size_t)E2 * DIM * 2);
    unsigned short* W_out_b = (unsigned short*)alloc((size_t)DIM * D_INNER * 2);
    unsigned short* W_x_b   = (unsigned short*)alloc((size_t)64 * D_INNER * 2);
    unsigned short* W_dt_b  = (unsigned short*)alloc((size_t)D_INNER * DT_RANK * 2);
    float* xdbl             = (float*)alloc((size_t)BL * 64 * 4);
    float* part             = (float*)alloc((size_t)XKS * BL * 64 * 4);
    unsigned short* Hc      = (unsigned short*)alloc((size_t)BATCH * NCHUNK * D_INNER * 16 * 2);
    float* sdt              = (float*)alloc((size_t)BATCH * NCHUNK * D_INNER * 4);

    // 0. all f32->bf16 conversions in one dispatch
    cvt5_kernel<<<(294912 + 196608 + 147456 + 12288 + 6144) / 256, 256, 0, stream>>>(
        W_in, W_in_b, E2 * DIM / 8,
        x, xb, BL * DIM / 8,
        W_out, W_out_b, DIM * D_INNER / 8,
        W_x, W_x_b, 64 * D_INNER / 8,
        W_dt, W_dt_b, D_INNER * DT_RANK / 8);
    // 1. xz = x @ W_in^T  (bf16 MFMA -> bf16 out, 128x128 tiles, 384 blocks)
    gemm_bf16<128, 128, 3><<<dim3(E2 / 128, BL / 128), 256, 0, stream>>>(
        xb, W_in_b, xzb, E2, nullptr, 0, DIM);
    // 2. depthwise causal conv + bias + silu (bf16 in/out, 8 ch/thread)
    conv_silu_kernel<<<(BL * D_INNER / 8) / 256, 256, 0, stream>>>(
        xzb, W_conv, b_conv, xcsb);
    // 3. x_dbl split-K MFMA GEMM + reduce (-> xdbl fp32, dt_lr bf16)
    xdbl_gemm<<<dim3(XKS, BL / 128), 256, 0, stream>>>(xcsb, W_x_b, part);
    xdbl_reduce<<<(BL * 64) / 256, 256, 0, stream>>>(part, xdbl, dtlrb);
    // 4. dt = softplus(dt_lr @ W_dt^T + 2 b_dt) -> bf16  (64x64, 768 blocks)
    gemm_bf16<64, 64, 1><<<dim3(D_INNER / 64, BL / 64), 256, 0, stream>>>(
        dtlrb, W_dt_b, dtgb, D_INNER, b_dt, 0, DT_RANK);
    // 5. 3-pass chunked selective scan (bf16 state, 4-deep pipelined combine)
    scan_p1<<<dim3(D_INNER / 256, NCHUNK, BATCH), 256, 0, stream>>>(
        dtgb, xcsb, xdbl, A_log, Hc, sdt);
    scan_p2<<<(BATCH * D_INNER * 16) / 256, 256, 0, stream>>>(Hc, sdt, A_log);
    scan_p3<<<dim3(D_INNER / 256, NCHUNK, BATCH), 256, 0, stream>>>(
        dtgb, xcsb, xdbl, A_log, Dp, Hc, xzb, ymb);
    // 6. out = ym @ W_out^T + x  (bf16 MFMA, 64x64 tiles, 384 blocks)
    gemm_bf16<64, 64, 2><<<dim3(DIM / 64, BL / 64), 256, 0, stream>>>(
        ymb, W_out_b, out, DIM, x, DIM, D_INNER);
}

// Round 18
// 102.517 us; speedup vs baseline: 1.2488x; 1.0557x over previous
//
#include <hip/hip_runtime.h>
#include <stdint.h>

#define DIM 768
#define D_STATE 16
#define D_CONV 4
#define DT_RANK 32
#define D_INNER 1536
#define BATCH 2
#define SEQ 1024
#define BL (BATCH * SEQ)   // 2048
#define E2 (2 * D_INNER)   // 3072
#define NCHUNK 64
#define TC (SEQ / NCHUNK)  // 16 steps per chunk
#define XKS 8              // split-K factor for x_dbl GEMM
#define XKC (D_INNER / XKS) // 192

typedef __attribute__((ext_vector_type(8))) __bf16 bf16x8;
typedef __attribute__((ext_vector_type(4))) float f32x4;
typedef __attribute__((ext_vector_type(8))) unsigned short u16x8;

__device__ __forceinline__ float silu_f(float v) {
    return v / (1.0f + __expf(-v));
}
// fast softplus: hardware exp/log path
__device__ __forceinline__ float softplus_f(float v) {
    return fmaxf(v, 0.0f) + __logf(1.0f + __expf(-fabsf(v)));
}
__device__ __forceinline__ unsigned short f2bf(float f) {
    uint32_t u = __float_as_uint(f);
    u += 0x7FFFu + ((u >> 16) & 1u);          // round-to-nearest-even
    return (unsigned short)(u >> 16);
}
__device__ __forceinline__ float bf2f(unsigned short u) {
    return __uint_as_float((uint32_t)u << 16);
}
// global -> LDS direct copy, 16B per lane. LDS dest: wave-uniform base + lane*16.
__device__ __forceinline__ void gload_lds16(const void* g, void* l) {
    __builtin_amdgcn_global_load_lds(
        (const __attribute__((address_space(1))) unsigned int*)(uintptr_t)g,
        (__attribute__((address_space(3))) unsigned int*)(uint32_t)(uintptr_t)l,
        16, 0, 0);
}
// counted vmcnt wait (immediate must be a literal)
template <int N> __device__ __forceinline__ void vmcnt_wait() {
    if constexpr (N == 0)      asm volatile("s_waitcnt vmcnt(0)" ::: "memory");
    else if constexpr (N == 1) asm volatile("s_waitcnt vmcnt(1)" ::: "memory");
    else if constexpr (N == 2) asm volatile("s_waitcnt vmcnt(2)" ::: "memory");
    else if constexpr (N == 3) asm volatile("s_waitcnt vmcnt(3)" ::: "memory");
    else if constexpr (N == 4) asm volatile("s_waitcnt vmcnt(4)" ::: "memory");
    else                       asm volatile("s_waitcnt vmcnt(6)" ::: "memory");
}

// ---------------------------------------------------------------------------
// Fused f32->bf16 conversion: W_in, x, W_out, W_x, W_dt in one dispatch.
// ---------------------------------------------------------------------------
__global__ __launch_bounds__(256) void cvt5_kernel(
    const float* __restrict__ s0, unsigned short* __restrict__ d0, int n0,
    const float* __restrict__ s1, unsigned short* __restrict__ d1, int n1,
    const float* __restrict__ s2, unsigned short* __restrict__ d2, int n2,
    const float* __restrict__ s3, unsigned short* __restrict__ d3, int n3,
    const float* __restrict__ s4, unsigned short* __restrict__ d4, int n4)
{
    int i = blockIdx.x * 256 + threadIdx.x;
    const float* s; unsigned short* d;
    if (i < n0)                          { s = s0; d = d0; }
    else if ((i -= n0) < n1)             { s = s1; d = d1; }
    else if ((i -= n1) < n2)             { s = s2; d = d2; }
    else if ((i -= n2) < n3)             { s = s3; d = d3; }
    else { i -= n3; if (i >= n4) return;   s = s4; d = d4; }
    const f32x4 a = ((const f32x4*)s)[2 * i];
    const f32x4 b = ((const f32x4*)s)[2 * i + 1];
    u16x8 o;
#pragma unroll
    for (int j = 0; j < 4; ++j) { o[j] = f2bf(a[j]); o[4 + j] = f2bf(b[j]); }
    ((u16x8*)d)[i] = o;
}

// ---------------------------------------------------------------------------
// bf16 MFMA GEMM, templated tile: C[M,N] = A[M,K]bf16 * B[N,K]^T bf16.
// 4 waves (2x2), 16x16x32 MFMA.  3-buffer LDS pipeline with COUNTED
// vmcnt(NC): two tiles in flight, wait covers loads issued 2 phases ago,
// drain-0 only in the peeled last iteration (T4 counted-vmcnt).
// EPI 0: f32 out.  EPI 1: softplus(acc+2*X[col]) -> bf16 out.
// EPI 2: acc + X[row*ldx+col] -> f32 out.  EPI 3: bf16 out.
// ---------------------------------------------------------------------------
template <int BM, int BN, int EPI>
__global__ __launch_bounds__(256) void gemm_bf16(
    const unsigned short* __restrict__ A, const unsigned short* __restrict__ B,
    void* __restrict__ C, int ldc,
    const float* __restrict__ X, int ldx, int K)
{
    constexpr int NROW = BM + BN;      // staged rows (A then B), 32 bf16 cols
    constexpr int RW = NROW / 4;       // rows per wave
    constexpr int NC = RW / 16;        // gload_lds16 calls per wave per tile
    constexpr int FM = BM / 32;        // frag rows per wave (2x2 wave grid)
    constexpr int FN = BN / 32;
    __shared__ __align__(16) unsigned short S[3][NROW * 32];
    const int tid = threadIdx.x;
    const int wid = tid >> 6;
    const int lane = tid & 63;
    const int wr = wid >> 1, wc = wid & 1;
    const int bm = blockIdx.y * BM, bn = blockIdx.x * BN;

    const int lrow = lane >> 2;
    const int scol = (lane & 3) * 8;
    const unsigned short* gsrc[NC];
#pragma unroll
    for (int c = 0; c < NC; ++c) {
        const int rowbase = wid * RW + c * 16;       // wave-uniform, %16==0
        const int grow = rowbase + lrow;
        gsrc[c] = (rowbase < BM)
            ? A + (size_t)(bm + grow) * K + scol
            : B + (size_t)(bn + grow - BM) * K + scol;
    }

    const int fr = lane & 15;
    const int fq = lane >> 4;
    f32x4 acc[FM][FN] = {};

    auto STAGE = [&](int nb, int k0) {
#pragma unroll
        for (int c = 0; c < NC; ++c)
            gload_lds16(gsrc[c] + k0, &S[nb][(wid * RW + c * 16) * 32]);
    };
    auto COMPUTE = [&](int cb) {
        bf16x8 af[FM], bfr[FN];
#pragma unroll
        for (int m = 0; m < FM; ++m)
            af[m] = *(const bf16x8*)&S[cb][(wr * (BM / 2) + m * 16 + fr) * 32 + fq * 8];
#pragma unroll
        for (int n = 0; n < FN; ++n)
            bfr[n] = *(const bf16x8*)&S[cb][(BM + wc * (BN / 2) + n * 16 + fr) * 32 + fq * 8];
#pragma unroll
        for (int m = 0; m < FM; ++m)
#pragma unroll
            for (int n = 0; n < FN; ++n)
                acc[m][n] = __builtin_amdgcn_mfma_f32_16x16x32_bf16(
                    af[m], bfr[n], acc[m][n], 0, 0, 0);
    };

    const int NT = K / 32;             // k-tiles
    STAGE(0, 0);
    if (NT > 1) STAGE(1, 32);
    int t = 0;
    for (; t < NT - 1; ++t) {
        vmcnt_wait<NC>();              // tile t done (t+1 stays in flight)
        __builtin_amdgcn_s_barrier();
        COMPUTE(t % 3);
        if (t + 2 < NT) STAGE((t + 2) % 3, (t + 2) * 32);
    }
    vmcnt_wait<0>();                   // last tile: full drain
    __builtin_amdgcn_s_barrier();
    COMPUTE(t % 3);

#pragma unroll
    for (int m = 0; m < FM; ++m) {
#pragma unroll
        for (int n = 0; n < FN; ++n) {
            const int col = bn + wc * (BN / 2) + n * 16 + fr;
#pragma unroll
            for (int r = 0; r < 4; ++r) {
                const int row = bm + wr * (BM / 2) + m * 16 + fq * 4 + r;
                float o = acc[m][n][r];
                if (EPI == 0) {
                    ((float*)C)[(size_t)row * ldc + col] = o;
                } else if (EPI == 1) {
                    o = softplus_f(o + 2.0f * X[col]);
                    ((unsigned short*)C)[(size_t)row * ldc + col] = f2bf(o);
                } else if (EPI == 2) {
                    o += X[(size_t)row * ldx + col];
                    ((float*)C)[(size_t)row * ldc + col] = o;
                } else {
                    ((unsigned short*)C)[(size_t)row * ldc + col] = f2bf(o);
                }
            }
        }
    }
}

// ---------------------------------------------------------------------------
// x_dbl GEMM, split-K (unchanged 2-buffer form).
// ---------------------------------------------------------------------------
__global__ __launch_bounds__(256) void xdbl_gemm(
    const unsigned short* __restrict__ xcsb,
    const unsigned short* __restrict__ W_x_b,
    float* __restrict__ part)
{
    constexpr int BM = 128, NROW = BM + 64, RW = NROW / 4, NC = RW / 16;
    __shared__ __align__(16) unsigned short S[2][NROW * 32];
    const int tid = threadIdx.x;
    const int wid = tid >> 6, lane = tid & 63;
    const int wr = wid >> 1, wc = wid & 1;
    const int bm = blockIdx.y * BM;
    const int kb = blockIdx.x * XKC;
    const int lrow = lane >> 2, scol = (lane & 3) * 8;
    const unsigned short* gsrc[NC];
#pragma unroll
    for (int c = 0; c < NC; ++c) {
        const int rowbase = wid * RW + c * 16;
        const int grow = rowbase + lrow;
        gsrc[c] = (rowbase < BM)
            ? xcsb + (size_t)(bm + grow) * D_INNER + kb + scol
            : W_x_b + (size_t)(grow - BM) * D_INNER + kb + scol;
    }
    const int fr = lane & 15, fq = lane >> 4;
    f32x4 acc[4][2] = {};
    auto STAGE = [&](int nb, int k0) {
#pragma unroll
        for (int c = 0; c < NC; ++c)
            gload_lds16(gsrc[c] + k0, &S[nb][(wid * RW + c * 16) * 32]);
    };
    auto COMPUTE = [&](int cb) {
        bf16x8 af[4], bfr[2];
#pragma unroll
        for (int m = 0; m < 4; ++m)
            af[m] = *(const bf16x8*)&S[cb][(wr * 64 + m * 16 + fr) * 32 + fq * 8];
#pragma unroll
        for (int n = 0; n < 2; ++n)
            bfr[n] = *(const bf16x8*)&S[cb][(BM + wc * 32 + n * 16 + fr) * 32 + fq * 8];
#pragma unroll
        for (int m = 0; m < 4; ++m)
#pragma unroll
            for (int n = 0; n < 2; ++n)
                acc[m][n] = __builtin_amdgcn_mfma_f32_16x16x32_bf16(
                    af[m], bfr[n], acc[m][n], 0, 0, 0);
    };
    STAGE(0, 0);
    asm volatile("s_waitcnt vmcnt(0)" ::: "memory");
    __builtin_amdgcn_s_barrier();
    int cur = 0;
    for (int k0 = 32; k0 < XKC; k0 += 32) {
        STAGE(cur ^ 1, k0);
        COMPUTE(cur);
        asm volatile("s_waitcnt vmcnt(0)" ::: "memory");
        __builtin_amdgcn_s_barrier();
        cur ^= 1;
    }
    COMPUTE(cur);
    float* P = part + (size_t)blockIdx.x * BL * 64;
#pragma unroll
    for (int m = 0; m < 4; ++m)
#pragma unroll
        for (int n = 0; n < 2; ++n) {
            const int col = wc * 32 + n * 16 + fr;
#pragma unroll
            for (int r = 0; r < 4; ++r) {
                const int row = bm + wr * 64 + m * 16 + fq * 4 + r;
                P[(size_t)row * 64 + col] = acc[m][n][r];
            }
        }
}

// ---------------------------------------------------------------------------
// Reduce split-K partials -> xdbl fp32 (B,C for scan) + dt_lr bf16 rows.
// ---------------------------------------------------------------------------
__global__ __launch_bounds__(256) void xdbl_reduce(
    const float* __restrict__ part, float* __restrict__ xdbl,
    unsigned short* __restrict__ dtlrb)
{
    const int i = blockIdx.x * 256 + threadIdx.x;   // over BL*64
    if (i >= BL * 64) return;
    float s = 0.0f;
#pragma unroll
    for (int ks = 0; ks < XKS; ++ks) s += part[(size_t)ks * (BL * 64) + i];
    xdbl[i] = s;
    const int col = i & 63, row = i >> 6;
    if (col < 32) dtlrb[row * 32 + col] = f2bf(s);
}

// ---------------------------------------------------------------------------
// Depthwise causal conv (k=4) + bias + SiLU, 8 channels/thread (vectorized).
// ---------------------------------------------------------------------------
__global__ __launch_bounds__(256) void conv_silu_kernel(
    const unsigned short* __restrict__ xzb, const float* __restrict__ Wc,
    const float* __restrict__ bc, unsigned short* __restrict__ xcsb)
{
    const int i8 = blockIdx.x * 256 + threadIdx.x;   // over BL*D_INNER/8
    if (i8 >= BL * D_INNER / 8) return;
    const int dg = i8 % (D_INNER / 8);
    const int bl = i8 / (D_INNER / 8);
    const int l = bl % SEQ;
    const int d0 = dg * 8;
    const size_t rowb = (size_t)bl * E2 + d0;

    const u16x8 x0 = *(const u16x8*)&xzb[rowb];
    u16x8 x1 = {}, x2 = {}, x3 = {};
    if (l >= 1) x1 = *(const u16x8*)&xzb[rowb - E2];
    if (l >= 2) x2 = *(const u16x8*)&xzb[rowb - 2 * E2];
    if (l >= 3) x3 = *(const u16x8*)&xzb[rowb - 3 * E2];
    const f32x4 b0 = *(const f32x4*)&bc[d0];
    const f32x4 b1 = *(const f32x4*)&bc[d0 + 4];

    u16x8 o;
#pragma unroll
    for (int j = 0; j < 8; ++j) {
        const f32x4 w = *(const f32x4*)&Wc[(size_t)(d0 + j) * 4];
        float acc = (j < 4 ? b0[j] : b1[j - 4]);
        acc += w[3] * bf2f(x0[j]);
        acc += w[2] * bf2f(x1[j]);   // zero-init vectors make l<3 taps 0
        acc += w[1] * bf2f(x2[j]);
        acc += w[0] * bf2f(x3[j]);
        o[j] = f2bf(silu_f(acc));
    }
    *(u16x8*)&xcsb[(size_t)bl * D_INNER + d0] = o;
}

// ---------------------------------------------------------------------------
// 3-pass chunked selective scan.  Hc/Hinit stored bf16;
// scan_p2 uses a 4-deep statically-indexed software pipeline.
// ---------------------------------------------------------------------------
__global__ __launch_bounds__(256) void scan_p1(
    const unsigned short* __restrict__ dtgb, const unsigned short* __restrict__ xcsb,
    const float* __restrict__ xdbl, const float* __restrict__ A_log,
    unsigned short* __restrict__ Hc, float* __restrict__ sdt_arr)
{
    __shared__ unsigned short dt_s[TC][256];
    __shared__ unsigned short xc_s[TC][256];
    __shared__ float Bsh[TC][16];
    const int tid = threadIdx.x;
    const int d0 = blockIdx.x * 256;
    const int d = d0 + tid;
    const int c = blockIdx.y;
    const int b = blockIdx.z;
    const int r0 = b * SEQ + c * TC;

#pragma unroll
    for (int k = 0; k < TC * 32 / 256; ++k) {
        const int u = k * 256 + tid;
        const int t = u >> 5, c8 = (u & 31) * 8;
        *(u16x8*)&dt_s[t][c8] = *(const u16x8*)&dtgb[(size_t)(r0 + t) * D_INNER + d0 + c8];
        *(u16x8*)&xc_s[t][c8] = *(const u16x8*)&xcsb[(size_t)(r0 + t) * D_INNER + d0 + c8];
    }
    {
        const int t = tid >> 4, j = tid & 15;
        Bsh[t][j] = xdbl[(size_t)(r0 + t) * 64 + 32 + j];
    }
    float a[16];
#pragma unroll
    for (int q = 0; q < 4; ++q) {
        const f32x4 al = *(const f32x4*)&A_log[(size_t)d * 16 + q * 4];
#pragma unroll
        for (int j = 0; j < 4; ++j) a[q * 4 + j] = -__expf(al[j]);
    }
    __syncthreads();

    float h[16];
#pragma unroll
    for (int s = 0; s < 16; ++s) h[s] = 0.0f;
    float sdt = 0.0f;
#pragma unroll
    for (int t = 0; t < TC; ++t) {
        const float dt = bf2f(dt_s[t][tid]);
        const float xc = bf2f(xc_s[t][tid]);
        sdt += dt;
        const float u = dt * xc;
        const f32x4 B0 = *(const f32x4*)&Bsh[t][0];
        const f32x4 B1 = *(const f32x4*)&Bsh[t][4];
        const f32x4 B2 = *(const f32x4*)&Bsh[t][8];
        const f32x4 B3 = *(const f32x4*)&Bsh[t][12];
#pragma unroll
        for (int s = 0; s < 16; ++s) {
            const float Bv = (s < 4 ? B0[s] : s < 8 ? B1[s - 4] : s < 12 ? B2[s - 8] : B3[s - 12]);
            h[s] = __expf(dt * a[s]) * h[s] + u * Bv;
        }
    }
    const size_t o = (((size_t)b * NCHUNK + c) * D_INNER + d) * 16;
    u16x8 h0, h1;
#pragma unroll
    for (int j = 0; j < 8; ++j) { h0[j] = f2bf(h[j]); h1[j] = f2bf(h[8 + j]); }
    *(u16x8*)&Hc[o] = h0;
    *(u16x8*)&Hc[o + 8] = h1;
    sdt_arr[((size_t)b * NCHUNK + c) * D_INNER + d] = sdt;
}

// 4-deep software-pipelined chunk combine (bf16 state).
__global__ __launch_bounds__(256) void scan_p2(
    unsigned short* __restrict__ Hc, const float* __restrict__ sdt_arr,
    const float* __restrict__ A_log)
{
    const int idx = blockIdx.x * 256 + threadIdx.x;
    if (idx >= BATCH * D_INNER * 16) return;
    const int b = idx / (D_INNER * 16);
    const int ds = idx % (D_INNER * 16);
    const int d = ds >> 4;
    const float a = -__expf(A_log[ds]);
    const size_t hstep = (size_t)D_INNER * 16;
    const size_t sstep = (size_t)D_INNER;
    size_t oh = (size_t)b * NCHUNK * hstep + ds;
    size_t os = (size_t)b * NCHUNK * sstep + d;

    // 4 named pipeline slots (static indexing only — rule #20)
    float hc0 = bf2f(Hc[oh]);             float sd0 = sdt_arr[os];
    float hc1 = bf2f(Hc[oh + hstep]);     float sd1 = sdt_arr[os + sstep];
    float hc2 = bf2f(Hc[oh + 2 * hstep]); float sd2 = sdt_arr[os + 2 * sstep];
    float hc3 = bf2f(Hc[oh + 3 * hstep]); float sd3 = sdt_arr[os + 3 * sstep];
    float h = 0.0f;

#pragma unroll
    for (int c = 0; c < NCHUNK; c += 4) {
        {
            const float E = __expf(sd0 * a);
            Hc[oh] = f2bf(h);
            h = E * h + hc0;
            if (c + 4 < NCHUNK) { hc0 = bf2f(Hc[oh + 4 * hstep]); sd0 = sdt_arr[os + 4 * sstep]; }
            oh += hstep; os += sstep;
        }
        {
            const float E = __expf(sd1 * a);
            Hc[oh] = f2bf(h);
            h = E * h + hc1;
            if (c + 5 < NCHUNK) { hc1 = bf2f(Hc[oh + 4 * hstep]); sd1 = sdt_arr[os + 4 * sstep]; }
            oh += hstep; os += sstep;
        }
        {
            const float E = __expf(sd2 * a);
            Hc[oh] = f2bf(h);
            h = E * h + hc2;
            if (c + 6 < NCHUNK) { hc2 = bf2f(Hc[oh + 4 * hstep]); sd2 = sdt_arr[os + 4 * sstep]; }
            oh += hstep; os += sstep;
        }
        {
            const float E = __expf(sd3 * a);
            Hc[oh] = f2bf(h);
            h = E * h + hc3;
            if (c + 7 < NCHUNK) { hc3 = bf2f(Hc[oh + 4 * hstep]); sd3 = sdt_arr[os + 4 * sstep]; }
            oh += hstep; os += sstep;
        }
    }
}

__global__ __launch_bounds__(256) void scan_p3(
    const unsigned short* __restrict__ dtgb, const unsigned short* __restrict__ xcsb,
    const float* __restrict__ xdbl, const float* __restrict__ A_log,
    const float* __restrict__ Dp, const unsigned short* __restrict__ Hinit,
    const unsigned short* __restrict__ xzb, unsigned short* __restrict__ ymb)
{
    __shared__ unsigned short dt_s[TC][256];
    __shared__ unsigned short xc_s[TC][256];
    __shared__ unsigned short z_s[TC][256];
    __shared__ float BCsh[TC][32];
    const int tid = threadIdx.x;
    const int d0 = blockIdx.x * 256;
    const int d = d0 + tid;
    const int c = blockIdx.y;
    const int b = blockIdx.z;
    const int r0 = b * SEQ + c * TC;

#pragma unroll
    for (int k = 0; k < TC * 32 / 256; ++k) {
        const int u = k * 256 + tid;
        const int t = u >> 5, c8 = (u & 31) * 8;
        *(u16x8*)&dt_s[t][c8] = *(const u16x8*)&dtgb[(size_t)(r0 + t) * D_INNER + d0 + c8];
        *(u16x8*)&xc_s[t][c8] = *(const u16x8*)&xcsb[(size_t)(r0 + t) * D_INNER + d0 + c8];
        *(u16x8*)&z_s[t][c8]  = *(const u16x8*)&xzb[(size_t)(r0 + t) * E2 + D_INNER + d0 + c8];
    }
    for (int i = tid; i < TC * 32; i += 256) {
        const int t = i >> 5, j = i & 31;
        BCsh[t][j] = xdbl[(size_t)(r0 + t) * 64 + 32 + j];
    }
    float a[16];
#pragma unroll
    for (int q = 0; q < 4; ++q) {
        const f32x4 al = *(const f32x4*)&A_log[(size_t)d * 16 + q * 4];
#pragma unroll
        for (int j = 0; j < 4; ++j) a[q * 4 + j] = -__expf(al[j]);
    }
    const float Dd = Dp[d];
    float h[16];
    {
        const size_t o = (((size_t)b * NCHUNK + c) * D_INNER + d) * 16;
        const u16x8 h0 = *(const u16x8*)&Hinit[o];
        const u16x8 h1 = *(const u16x8*)&Hinit[o + 8];
#pragma unroll
        for (int j = 0; j < 8; ++j) { h[j] = bf2f(h0[j]); h[8 + j] = bf2f(h1[j]); }
    }
    __syncthreads();

    const size_t base = (size_t)r0 * D_INNER + d;
#pragma unroll
    for (int t = 0; t < TC; ++t) {
        const float dt = bf2f(dt_s[t][tid]);
        const float xc = bf2f(xc_s[t][tid]);
        const float z  = bf2f(z_s[t][tid]);
        const float u = dt * xc;
        const f32x4 B0 = *(const f32x4*)&BCsh[t][0];
        const f32x4 B1 = *(const f32x4*)&BCsh[t][4];
        const f32x4 B2 = *(const f32x4*)&BCsh[t][8];
        const f32x4 B3 = *(const f32x4*)&BCsh[t][12];
        const f32x4 C0 = *(const f32x4*)&BCsh[t][16];
        const f32x4 C1 = *(const f32x4*)&BCsh[t][20];
        const f32x4 C2 = *(const f32x4*)&BCsh[t][24];
        const f32x4 C3 = *(const f32x4*)&BCsh[t][28];
        float y = 0.0f;
#pragma unroll
        for (int s = 0; s < 16; ++s) {
            const float Bv = (s < 4 ? B0[s] : s < 8 ? B1[s - 4] : s < 12 ? B2[s - 8] : B3[s - 12]);
            const float Cv = (s < 4 ? C0[s] : s < 8 ? C1[s - 4] : s < 12 ? C2[s - 8] : C3[s - 12]);
            h[s] = __expf(dt * a[s]) * h[s] + u * Bv;
            y += h[s] * Cv;
        }
        y += xc * Dd;
        ymb[base + (size_t)t * D_INNER] = f2bf(y * silu_f(z));
    }
}

extern "C" void kernel_launch(void* const* d_in, const int* in_sizes, int n_in,
                              void* d_out, int out_size, void* d_ws, size_t ws_size,
                              hipStream_t stream) {
    const float* x      = (const float*)d_in[0];
    const float* W_in   = (const float*)d_in[1];
    const float* W_conv = (const float*)d_in[2];
    const float* b_conv = (const float*)d_in[3];
    const float* W_x    = (const float*)d_in[4];
    const float* W_dt   = (const float*)d_in[5];
    const float* b_dt   = (const float*)d_in[6];
    const float* A_log  = (const float*)d_in[7];
    const float* Dp     = (const float*)d_in[8];
    const float* W_out  = (const float*)d_in[9];
    float* out = (float*)d_out;

    // linear workspace layout (all bf16 intermediates)
    char* p = (char*)d_ws;
    auto alloc = [&](size_t bytes) { char* r = p; p += (bytes + 255) & ~(size_t)255; return r; };
    unsigned short* xzb     = (unsigned short*)alloc((size_t)BL * E2 * 2);
    unsigned short* xcsb    = (unsigned short*)alloc((size_t)BL * D_INNER * 2);
    unsigned short* dtgb    = (unsigned short*)alloc((size_t)BL * D_INNER * 2);
    unsigned short* ymb     = (unsigned short*)alloc((size_t)BL * D_INNER * 2);
    unsigned short* dtlrb   = (unsigned short*)alloc((size_t)BL * 32 * 2);
    unsigned short* xb      = (unsigned short*)alloc((size_t)BL * DIM * 2);
    unsigned short* W_in_b  = (unsigned short*)alloc((size_t)E2 * DIM * 2);
    unsigned short* W_out_b = (unsigned short*)alloc((size_t)DIM * D_INNER * 2);
    unsigned short* W_x_b   = (unsigned short*)alloc((size_t)64 * D_INNER * 2);
    unsigned short* W_dt_b  = (unsigned short*)alloc((size_t)D_INNER * DT_RANK * 2);
    float* xdbl             = (float*)alloc((size_t)BL * 64 * 4);
    float* part             = (float*)alloc((size_t)XKS * BL * 64 * 4);
    unsigned short* Hc      = (unsigned short*)alloc((size_t)BATCH * NCHUNK * D_INNER * 16 * 2);
    float* sdt              = (float*)alloc((size_t)BATCH * NCHUNK * D_INNER * 4);

    // 0. all f32->bf16 conversions in one dispatch
    cvt5_kernel<<<(294912 + 196608 + 147456 + 12288 + 6144) / 256, 256, 0, stream>>>(
        W_in, W_in_b, E2 * DIM / 8,
        x, xb, BL * DIM / 8,
        W_out, W_out_b, DIM * D_INNER / 8,
        W_x, W_x_b, 64 * D_INNER / 8,
        W_dt, W_dt_b, D_INNER * DT_RANK / 8);
    // 1. xz = x @ W_in^T  (bf16 MFMA -> bf16 out, 128x128 tiles, 384 blocks)
    gemm_bf16<128, 128, 3><<<dim3(E2 / 128, BL / 128), 256, 0, stream>>>(
        xb, W_in_b, xzb, E2, nullptr, 0, DIM);
    // 2. depthwise causal conv + bias + silu (bf16 in/out, 8 ch/thread)
    conv_silu_kernel<<<(BL * D_INNER / 8) / 256, 256, 0, stream>>>(
        xzb, W_conv, b_conv, xcsb);
    // 3. x_dbl split-K MFMA GEMM + reduce (-> xdbl fp32, dt_lr bf16)
    xdbl_gemm<<<dim3(XKS, BL / 128), 256, 0, stream>>>(xcsb, W_x_b, part);
    xdbl_reduce<<<(BL * 64) / 256, 256, 0, stream>>>(part, xdbl, dtlrb);
    // 4. dt = softplus(dt_lr @ W_dt^T + 2 b_dt) -> bf16  (64x64, 768 blocks)
    gemm_bf16<64, 64, 1><<<dim3(D_INNER / 64, BL / 64), 256, 0, stream>>>(
        dtlrb, W_dt_b, dtgb, D_INNER, b_dt, 0, DT_RANK);
    // 5. 3-pass chunked selective scan (bf16 state, 4-deep pipelined combine)
    scan_p1<<<dim3(D_INNER / 256, NCHUNK, BATCH), 256, 0, stream>>>(
        dtgb, xcsb, xdbl, A_log, Hc, sdt);
    scan_p2<<<(BATCH * D_INNER * 16) / 256, 256, 0, stream>>>(Hc, sdt, A_log);
    scan_p3<<<dim3(D_INNER / 256, NCHUNK, BATCH), 256, 0, stream>>>(
        dtgb, xcsb, xdbl, A_log, Dp, Hc, xzb, ymb);
    // 6. out = ym @ W_out^T + x  (bf16 MFMA, 64x64 tiles, 384 blocks)
    gemm_bf16<64, 64, 2><<<dim3(DIM / 64, BL / 64), 256, 0, stream>>>(
        ymb, W_out_b, out, DIM, x, DIM, D_INNER);
}

// Round 19
// 102.235 us; speedup vs baseline: 1.2523x; 1.0028x over previous
//
#include <hip/hip_runtime.h>
#include <stdint.h>

#define DIM 768
#define D_STATE 16
#define D_CONV 4
#define DT_RANK 32
#define D_INNER 1536
#define BATCH 2
#define SEQ 1024
#define BL (BATCH * SEQ)   // 2048
#define E2 (2 * D_INNER)   // 3072
#define NCHUNK 64
#define TC (SEQ / NCHUNK)  // 16 steps per chunk
#define XKS 8              // split-K factor for x_dbl GEMM
#define XKC (D_INNER / XKS) // 192

typedef __attribute__((ext_vector_type(8))) __bf16 bf16x8;
typedef __attribute__((ext_vector_type(4))) float f32x4;
typedef __attribute__((ext_vector_type(8))) unsigned short u16x8;

__device__ __forceinline__ float silu_f(float v) {
    return v / (1.0f + __expf(-v));
}
// fast softplus: hardware exp/log path
__device__ __forceinline__ float softplus_f(float v) {
    return fmaxf(v, 0.0f) + __logf(1.0f + __expf(-fabsf(v)));
}
__device__ __forceinline__ unsigned short f2bf(float f) {
    uint32_t u = __float_as_uint(f);
    u += 0x7FFFu + ((u >> 16) & 1u);          // round-to-nearest-even
    return (unsigned short)(u >> 16);
}
__device__ __forceinline__ float bf2f(unsigned short u) {
    return __uint_as_float((uint32_t)u << 16);
}
// global -> LDS direct copy, 16B per lane. LDS dest: wave-uniform base + lane*16.
__device__ __forceinline__ void gload_lds16(const void* g, void* l) {
    __builtin_amdgcn_global_load_lds(
        (const __attribute__((address_space(1))) unsigned int*)(uintptr_t)g,
        (__attribute__((address_space(3))) unsigned int*)(uint32_t)(uintptr_t)l,
        16, 0, 0);
}
// counted vmcnt wait (immediate must be a literal)
template <int N> __device__ __forceinline__ void vmcnt_wait() {
    if constexpr (N == 0)      asm volatile("s_waitcnt vmcnt(0)" ::: "memory");
    else if constexpr (N == 1) asm volatile("s_waitcnt vmcnt(1)" ::: "memory");
    else if constexpr (N == 2) asm volatile("s_waitcnt vmcnt(2)" ::: "memory");
    else if constexpr (N == 3) asm volatile("s_waitcnt vmcnt(3)" ::: "memory");
    else if constexpr (N == 4) asm volatile("s_waitcnt vmcnt(4)" ::: "memory");
    else                       asm volatile("s_waitcnt vmcnt(6)" ::: "memory");
}

// ---------------------------------------------------------------------------
// Fused f32->bf16 conversion: W_in, x, W_out, W_x, W_dt in one dispatch.
// ---------------------------------------------------------------------------
__global__ __launch_bounds__(256) void cvt5_kernel(
    const float* __restrict__ s0, unsigned short* __restrict__ d0, int n0,
    const float* __restrict__ s1, unsigned short* __restrict__ d1, int n1,
    const float* __restrict__ s2, unsigned short* __restrict__ d2, int n2,
    const float* __restrict__ s3, unsigned short* __restrict__ d3, int n3,
    const float* __restrict__ s4, unsigned short* __restrict__ d4, int n4)
{
    int i = blockIdx.x * 256 + threadIdx.x;
    const float* s; unsigned short* d;
    if (i < n0)                          { s = s0; d = d0; }
    else if ((i -= n0) < n1)             { s = s1; d = d1; }
    else if ((i -= n1) < n2)             { s = s2; d = d2; }
    else if ((i -= n2) < n3)             { s = s3; d = d3; }
    else { i -= n3; if (i >= n4) return;   s = s4; d = d4; }
    const f32x4 a = ((const f32x4*)s)[2 * i];
    const f32x4 b = ((const f32x4*)s)[2 * i + 1];
    u16x8 o;
#pragma unroll
    for (int j = 0; j < 4; ++j) { o[j] = f2bf(a[j]); o[4 + j] = f2bf(b[j]); }
    ((u16x8*)d)[i] = o;
}

// ---------------------------------------------------------------------------
// bf16 MFMA GEMM, templated tile: C[M,N] = A[M,K]bf16 * B[N,K]^T bf16.
// 4 waves (2x2), 16x16x32 MFMA.  3-buffer LDS pipeline with COUNTED
// vmcnt(NC): two tiles in flight, drain-0 only in the peeled last iter.
// EPI 0: f32 out.  EPI 1: softplus(acc+2*X[col]) -> bf16 out.
// EPI 2: acc + X[row*ldx+col] -> f32 out.  EPI 3: bf16 out.
// ---------------------------------------------------------------------------
template <int BM, int BN, int EPI>
__global__ __launch_bounds__(256) void gemm_bf16(
    const unsigned short* __restrict__ A, const unsigned short* __restrict__ B,
    void* __restrict__ C, int ldc,
    const float* __restrict__ X, int ldx, int K)
{
    constexpr int NROW = BM + BN;      // staged rows (A then B), 32 bf16 cols
    constexpr int RW = NROW / 4;       // rows per wave
    constexpr int NC = RW / 16;        // gload_lds16 calls per wave per tile
    constexpr int FM = BM / 32;        // frag rows per wave (2x2 wave grid)
    constexpr int FN = BN / 32;
    __shared__ __align__(16) unsigned short S[3][NROW * 32];
    const int tid = threadIdx.x;
    const int wid = tid >> 6;
    const int lane = tid & 63;
    const int wr = wid >> 1, wc = wid & 1;
    const int bm = blockIdx.y * BM, bn = blockIdx.x * BN;

    const int lrow = lane >> 2;
    const int scol = (lane & 3) * 8;
    const unsigned short* gsrc[NC];
#pragma unroll
    for (int c = 0; c < NC; ++c) {
        const int rowbase = wid * RW + c * 16;       // wave-uniform, %16==0
        const int grow = rowbase + lrow;
        gsrc[c] = (rowbase < BM)
            ? A + (size_t)(bm + grow) * K + scol
            : B + (size_t)(bn + grow - BM) * K + scol;
    }

    const int fr = lane & 15;
    const int fq = lane >> 4;
    f32x4 acc[FM][FN] = {};

    auto STAGE = [&](int nb, int k0) {
#pragma unroll
        for (int c = 0; c < NC; ++c)
            gload_lds16(gsrc[c] + k0, &S[nb][(wid * RW + c * 16) * 32]);
    };
    auto COMPUTE = [&](int cb) {
        bf16x8 af[FM], bfr[FN];
#pragma unroll
        for (int m = 0; m < FM; ++m)
            af[m] = *(const bf16x8*)&S[cb][(wr * (BM / 2) + m * 16 + fr) * 32 + fq * 8];
#pragma unroll
        for (int n = 0; n < FN; ++n)
            bfr[n] = *(const bf16x8*)&S[cb][(BM + wc * (BN / 2) + n * 16 + fr) * 32 + fq * 8];
#pragma unroll
        for (int m = 0; m < FM; ++m)
#pragma unroll
            for (int n = 0; n < FN; ++n)
                acc[m][n] = __builtin_amdgcn_mfma_f32_16x16x32_bf16(
                    af[m], bfr[n], acc[m][n], 0, 0, 0);
    };

    const int NT = K / 32;             // k-tiles
    STAGE(0, 0);
    if (NT > 1) STAGE(1, 32);
    int t = 0;
    for (; t < NT - 1; ++t) {
        vmcnt_wait<NC>();              // tile t done (t+1 stays in flight)
        __builtin_amdgcn_s_barrier();
        COMPUTE(t % 3);
        if (t + 2 < NT) STAGE((t + 2) % 3, (t + 2) * 32);
    }
    vmcnt_wait<0>();                   // last tile: full drain
    __builtin_amdgcn_s_barrier();
    COMPUTE(t % 3);

#pragma unroll
    for (int m = 0; m < FM; ++m) {
#pragma unroll
        for (int n = 0; n < FN; ++n) {
            const int col = bn + wc * (BN / 2) + n * 16 + fr;
#pragma unroll
            for (int r = 0; r < 4; ++r) {
                const int row = bm + wr * (BM / 2) + m * 16 + fq * 4 + r;
                float o = acc[m][n][r];
                if (EPI == 0) {
                    ((float*)C)[(size_t)row * ldc + col] = o;
                } else if (EPI == 1) {
                    o = softplus_f(o + 2.0f * X[col]);
                    ((unsigned short*)C)[(size_t)row * ldc + col] = f2bf(o);
                } else if (EPI == 2) {
                    o += X[(size_t)row * ldx + col];
                    ((float*)C)[(size_t)row * ldc + col] = o;
                } else {
                    ((unsigned short*)C)[(size_t)row * ldc + col] = f2bf(o);
                }
            }
        }
    }
}

// ---------------------------------------------------------------------------
// x_dbl GEMM, split-K: part[ks][M][64] = xcsb[M, ks*192:+192] @ W_x^T chunk.
// 3-buffer counted-vmcnt pipeline (same scheme as gemm_bf16), NT=6.
// ---------------------------------------------------------------------------
__global__ __launch_bounds__(256) void xdbl_gemm(
    const unsigned short* __restrict__ xcsb,
    const unsigned short* __restrict__ W_x_b,
    float* __restrict__ part)
{
    constexpr int BM = 128, NROW = BM + 64, RW = NROW / 4, NC = RW / 16;
    __shared__ __align__(16) unsigned short S[3][NROW * 32];
    const int tid = threadIdx.x;
    const int wid = tid >> 6, lane = tid & 63;
    const int wr = wid >> 1, wc = wid & 1;
    const int bm = blockIdx.y * BM;
    const int kb = blockIdx.x * XKC;
    const int lrow = lane >> 2, scol = (lane & 3) * 8;
    const unsigned short* gsrc[NC];
#pragma unroll
    for (int c = 0; c < NC; ++c) {
        const int rowbase = wid * RW + c * 16;
        const int grow = rowbase + lrow;
        gsrc[c] = (rowbase < BM)
            ? xcsb + (size_t)(bm + grow) * D_INNER + kb + scol
            : W_x_b + (size_t)(grow - BM) * D_INNER + kb + scol;
    }
    const int fr = lane & 15, fq = lane >> 4;
    f32x4 acc[4][2] = {};
    auto STAGE = [&](int nb, int k0) {
#pragma unroll
        for (int c = 0; c < NC; ++c)
            gload_lds16(gsrc[c] + k0, &S[nb][(wid * RW + c * 16) * 32]);
    };
    auto COMPUTE = [&](int cb) {
        bf16x8 af[4], bfr[2];
#pragma unroll
        for (int m = 0; m < 4; ++m)
            af[m] = *(const bf16x8*)&S[cb][(wr * 64 + m * 16 + fr) * 32 + fq * 8];
#pragma unroll
        for (int n = 0; n < 2; ++n)
            bfr[n] = *(const bf16x8*)&S[cb][(BM + wc * 32 + n * 16 + fr) * 32 + fq * 8];
#pragma unroll
        for (int m = 0; m < 4; ++m)
#pragma unroll
            for (int n = 0; n < 2; ++n)
                acc[m][n] = __builtin_amdgcn_mfma_f32_16x16x32_bf16(
                    af[m], bfr[n], acc[m][n], 0, 0, 0);
    };

    constexpr int NT = XKC / 32;       // 6 k-tiles
    STAGE(0, 0);
    STAGE(1, 32);
    int t = 0;
    for (; t < NT - 1; ++t) {
        vmcnt_wait<NC>();
        __builtin_amdgcn_s_barrier();
        COMPUTE(t % 3);
        if (t + 2 < NT) STAGE((t + 2) % 3, (t + 2) * 32);
    }
    vmcnt_wait<0>();
    __builtin_amdgcn_s_barrier();
    COMPUTE(t % 3);

    float* P = part + (size_t)blockIdx.x * BL * 64;
#pragma unroll
    for (int m = 0; m < 4; ++m)
#pragma unroll
        for (int n = 0; n < 2; ++n) {
            const int col = wc * 32 + n * 16 + fr;
#pragma unroll
            for (int r = 0; r < 4; ++r) {
                const int row = bm + wr * 64 + m * 16 + fq * 4 + r;
                P[(size_t)row * 64 + col] = acc[m][n][r];
            }
        }
}

// ---------------------------------------------------------------------------
// Reduce split-K partials -> xdbl fp32 (B,C for scan) + dt_lr bf16 rows.
// ---------------------------------------------------------------------------
__global__ __launch_bounds__(256) void xdbl_reduce(
    const float* __restrict__ part, float* __restrict__ xdbl,
    unsigned short* __restrict__ dtlrb)
{
    const int i = blockIdx.x * 256 + threadIdx.x;   // over BL*64
    if (i >= BL * 64) return;
    float s = 0.0f;
#pragma unroll
    for (int ks = 0; ks < XKS; ++ks) s += part[(size_t)ks * (BL * 64) + i];
    xdbl[i] = s;
    const int col = i & 63, row = i >> 6;
    if (col < 32) dtlrb[row * 32 + col] = f2bf(s);
}

// ---------------------------------------------------------------------------
// Depthwise causal conv (k=4) + bias + SiLU, 8 channels/thread (vectorized).
// ---------------------------------------------------------------------------
__global__ __launch_bounds__(256) void conv_silu_kernel(
    const unsigned short* __restrict__ xzb, const float* __restrict__ Wc,
    const float* __restrict__ bc, unsigned short* __restrict__ xcsb)
{
    const int i8 = blockIdx.x * 256 + threadIdx.x;   // over BL*D_INNER/8
    if (i8 >= BL * D_INNER / 8) return;
    const int dg = i8 % (D_INNER / 8);
    const int bl = i8 / (D_INNER / 8);
    const int l = bl % SEQ;
    const int d0 = dg * 8;
    const size_t rowb = (size_t)bl * E2 + d0;

    const u16x8 x0 = *(const u16x8*)&xzb[rowb];
    u16x8 x1 = {}, x2 = {}, x3 = {};
    if (l >= 1) x1 = *(const u16x8*)&xzb[rowb - E2];
    if (l >= 2) x2 = *(const u16x8*)&xzb[rowb - 2 * E2];
    if (l >= 3) x3 = *(const u16x8*)&xzb[rowb - 3 * E2];
    const f32x4 b0 = *(const f32x4*)&bc[d0];
    const f32x4 b1 = *(const f32x4*)&bc[d0 + 4];

    u16x8 o;
#pragma unroll
    for (int j = 0; j < 8; ++j) {
        const f32x4 w = *(const f32x4*)&Wc[(size_t)(d0 + j) * 4];
        float acc = (j < 4 ? b0[j] : b1[j - 4]);
        acc += w[3] * bf2f(x0[j]);
        acc += w[2] * bf2f(x1[j]);   // zero-init vectors make l<3 taps 0
        acc += w[1] * bf2f(x2[j]);
        acc += w[0] * bf2f(x3[j]);
        o[j] = f2bf(silu_f(acc));
    }
    *(u16x8*)&xcsb[(size_t)bl * D_INNER + d0] = o;
}

// ---------------------------------------------------------------------------
// 3-pass chunked selective scan.  Hc/Hinit stored bf16;
// scan_p2 uses a 4-deep statically-indexed software pipeline.
// ---------------------------------------------------------------------------
__global__ __launch_bounds__(256) void scan_p1(
    const unsigned short* __restrict__ dtgb, const unsigned short* __restrict__ xcsb,
    const float* __restrict__ xdbl, const float* __restrict__ A_log,
    unsigned short* __restrict__ Hc, float* __restrict__ sdt_arr)
{
    __shared__ unsigned short dt_s[TC][256];
    __shared__ unsigned short xc_s[TC][256];
    __shared__ float Bsh[TC][16];
    const int tid = threadIdx.x;
    const int d0 = blockIdx.x * 256;
    const int d = d0 + tid;
    const int c = blockIdx.y;
    const int b = blockIdx.z;
    const int r0 = b * SEQ + c * TC;

#pragma unroll
    for (int k = 0; k < TC * 32 / 256; ++k) {
        const int u = k * 256 + tid;
        const int t = u >> 5, c8 = (u & 31) * 8;
        *(u16x8*)&dt_s[t][c8] = *(const u16x8*)&dtgb[(size_t)(r0 + t) * D_INNER + d0 + c8];
        *(u16x8*)&xc_s[t][c8] = *(const u16x8*)&xcsb[(size_t)(r0 + t) * D_INNER + d0 + c8];
    }
    {
        const int t = tid >> 4, j = tid & 15;
        Bsh[t][j] = xdbl[(size_t)(r0 + t) * 64 + 32 + j];
    }
    float a[16];
#pragma unroll
    for (int q = 0; q < 4; ++q) {
        const f32x4 al = *(const f32x4*)&A_log[(size_t)d * 16 + q * 4];
#pragma unroll
        for (int j = 0; j < 4; ++j) a[q * 4 + j] = -__expf(al[j]);
    }
    __syncthreads();

    float h[16];
#pragma unroll
    for (int s = 0; s < 16; ++s) h[s] = 0.0f;
    float sdt = 0.0f;
#pragma unroll
    for (int t = 0; t < TC; ++t) {
        const float dt = bf2f(dt_s[t][tid]);
        const float xc = bf2f(xc_s[t][tid]);
        sdt += dt;
        const float u = dt * xc;
        const f32x4 B0 = *(const f32x4*)&Bsh[t][0];
        const f32x4 B1 = *(const f32x4*)&Bsh[t][4];
        const f32x4 B2 = *(const f32x4*)&Bsh[t][8];
        const f32x4 B3 = *(const f32x4*)&Bsh[t][12];
#pragma unroll
        for (int s = 0; s < 16; ++s) {
            const float Bv = (s < 4 ? B0[s] : s < 8 ? B1[s - 4] : s < 12 ? B2[s - 8] : B3[s - 12]);
            h[s] = __expf(dt * a[s]) * h[s] + u * Bv;
        }
    }
    const size_t o = (((size_t)b * NCHUNK + c) * D_INNER + d) * 16;
    u16x8 h0, h1;
#pragma unroll
    for (int j = 0; j < 8; ++j) { h0[j] = f2bf(h[j]); h1[j] = f2bf(h[8 + j]); }
    *(u16x8*)&Hc[o] = h0;
    *(u16x8*)&Hc[o + 8] = h1;
    sdt_arr[((size_t)b * NCHUNK + c) * D_INNER + d] = sdt;
}

// 4-deep software-pipelined chunk combine (bf16 state).
__global__ __launch_bounds__(256) void scan_p2(
    unsigned short* __restrict__ Hc, const float* __restrict__ sdt_arr,
    const float* __restrict__ A_log)
{
    const int idx = blockIdx.x * 256 + threadIdx.x;
    if (idx >= BATCH * D_INNER * 16) return;
    const int b = idx / (D_INNER * 16);
    const int ds = idx % (D_INNER * 16);
    const int d = ds >> 4;
    const float a = -__expf(A_log[ds]);
    const size_t hstep = (size_t)D_INNER * 16;
    const size_t sstep = (size_t)D_INNER;
    size_t oh = (size_t)b * NCHUNK * hstep + ds;
    size_t os = (size_t)b * NCHUNK * sstep + d;

    // 4 named pipeline slots (static indexing only — rule #20)
    float hc0 = bf2f(Hc[oh]);             float sd0 = sdt_arr[os];
    float hc1 = bf2f(Hc[oh + hstep]);     float sd1 = sdt_arr[os + sstep];
    float hc2 = bf2f(Hc[oh + 2 * hstep]); float sd2 = sdt_arr[os + 2 * sstep];
    float hc3 = bf2f(Hc[oh + 3 * hstep]); float sd3 = sdt_arr[os + 3 * sstep];
    float h = 0.0f;

#pragma unroll
    for (int c = 0; c < NCHUNK; c += 4) {
        {
            const float E = __expf(sd0 * a);
            Hc[oh] = f2bf(h);
            h = E * h + hc0;
            if (c + 4 < NCHUNK) { hc0 = bf2f(Hc[oh + 4 * hstep]); sd0 = sdt_arr[os + 4 * sstep]; }
            oh += hstep; os += sstep;
        }
        {
            const float E = __expf(sd1 * a);
            Hc[oh] = f2bf(h);
            h = E * h + hc1;
            if (c + 5 < NCHUNK) { hc1 = bf2f(Hc[oh + 4 * hstep]); sd1 = sdt_arr[os + 4 * sstep]; }
            oh += hstep; os += sstep;
        }
        {
            const float E = __expf(sd2 * a);
            Hc[oh] = f2bf(h);
            h = E * h + hc2;
            if (c + 6 < NCHUNK) { hc2 = bf2f(Hc[oh + 4 * hstep]); sd2 = sdt_arr[os + 4 * sstep]; }
            oh += hstep; os += sstep;
        }
        {
            const float E = __expf(sd3 * a);
            Hc[oh] = f2bf(h);
            h = E * h + hc3;
            if (c + 7 < NCHUNK) { hc3 = bf2f(Hc[oh + 4 * hstep]); sd3 = sdt_arr[os + 4 * sstep]; }
            oh += hstep; os += sstep;
        }
    }
}

__global__ __launch_bounds__(256) void scan_p3(
    const unsigned short* __restrict__ dtgb, const unsigned short* __restrict__ xcsb,
    const float* __restrict__ xdbl, const float* __restrict__ A_log,
    const float* __restrict__ Dp, const unsigned short* __restrict__ Hinit,
    const unsigned short* __restrict__ xzb, unsigned short* __restrict__ ymb)
{
    __shared__ unsigned short dt_s[TC][256];
    __shared__ unsigned short xc_s[TC][256];
    __shared__ unsigned short z_s[TC][256];
    __shared__ float BCsh[TC][32];
    const int tid = threadIdx.x;
    const int d0 = blockIdx.x * 256;
    const int d = d0 + tid;
    const int c = blockIdx.y;
    const int b = blockIdx.z;
    const int r0 = b * SEQ + c * TC;

#pragma unroll
    for (int k = 0; k < TC * 32 / 256; ++k) {
        const int u = k * 256 + tid;
        const int t = u >> 5, c8 = (u & 31) * 8;
        *(u16x8*)&dt_s[t][c8] = *(const u16x8*)&dtgb[(size_t)(r0 + t) * D_INNER + d0 + c8];
        *(u16x8*)&xc_s[t][c8] = *(const u16x8*)&xcsb[(size_t)(r0 + t) * D_INNER + d0 + c8];
        *(u16x8*)&z_s[t][c8]  = *(const u16x8*)&xzb[(size_t)(r0 + t) * E2 + D_INNER + d0 + c8];
    }
    for (int i = tid; i < TC * 32; i += 256) {
        const int t = i >> 5, j = i & 31;
        BCsh[t][j] = xdbl[(size_t)(r0 + t) * 64 + 32 + j];
    }
    float a[16];
#pragma unroll
    for (int q = 0; q < 4; ++q) {
        const f32x4 al = *(const f32x4*)&A_log[(size_t)d * 16 + q * 4];
#pragma unroll
        for (int j = 0; j < 4; ++j) a[q * 4 + j] = -__expf(al[j]);
    }
    const float Dd = Dp[d];
    float h[16];
    {
        const size_t o = (((size_t)b * NCHUNK + c) * D_INNER + d) * 16;
        const u16x8 h0 = *(const u16x8*)&Hinit[o];
        const u16x8 h1 = *(const u16x8*)&Hinit[o + 8];
#pragma unroll
        for (int j = 0; j < 8; ++j) { h[j] = bf2f(h0[j]); h[8 + j] = bf2f(h1[j]); }
    }
    __syncthreads();

    const size_t base = (size_t)r0 * D_INNER + d;
#pragma unroll
    for (int t = 0; t < TC; ++t) {
        const float dt = bf2f(dt_s[t][tid]);
        const float xc = bf2f(xc_s[t][tid]);
        const float z  = bf2f(z_s[t][tid]);
        const float u = dt * xc;
        const f32x4 B0 = *(const f32x4*)&BCsh[t][0];
        const f32x4 B1 = *(const f32x4*)&BCsh[t][4];
        const f32x4 B2 = *(const f32x4*)&BCsh[t][8];
        const f32x4 B3 = *(const f32x4*)&BCsh[t][12];
        const f32x4 C0 = *(const f32x4*)&BCsh[t][16];
        const f32x4 C1 = *(const f32x4*)&BCsh[t][20];
        const f32x4 C2 = *(const f32x4*)&BCsh[t][24];
        const f32x4 C3 = *(const f32x4*)&BCsh[t][28];
        float y = 0.0f;
#pragma unroll
        for (int s = 0; s < 16; ++s) {
            const float Bv = (s < 4 ? B0[s] : s < 8 ? B1[s - 4] : s < 12 ? B2[s - 8] : B3[s - 12]);
            const float Cv = (s < 4 ? C0[s] : s < 8 ? C1[s - 4] : s < 12 ? C2[s - 8] : C3[s - 12]);
            h[s] = __expf(dt * a[s]) * h[s] + u * Bv;
            y += h[s] * Cv;
        }
        y += xc * Dd;
        ymb[base + (size_t)t * D_INNER] = f2bf(y * silu_f(z));
    }
}

extern "C" void kernel_launch(void* const* d_in, const int* in_sizes, int n_in,
                              void* d_out, int out_size, void* d_ws, size_t ws_size,
                              hipStream_t stream) {
    const float* x      = (const float*)d_in[0];
    const float* W_in   = (const float*)d_in[1];
    const float* W_conv = (const float*)d_in[2];
    const float* b_conv = (const float*)d_in[3];
    const float* W_x    = (const float*)d_in[4];
    const float* W_dt   = (const float*)d_in[5];
    const float* b_dt   = (const float*)d_in[6];
    const float* A_log  = (const float*)d_in[7];
    const float* Dp     = (const float*)d_in[8];
    const float* W_out  = (const float*)d_in[9];
    float* out = (float*)d_out;

    // linear workspace layout (all bf16 intermediates)
    char* p = (char*)d_ws;
    auto alloc = [&](size_t bytes) { char* r = p; p += (bytes + 255) & ~(size_t)255; return r; };
    unsigned short* xzb     = (unsigned short*)alloc((size_t)BL * E2 * 2);
    unsigned short* xcsb    = (unsigned short*)alloc((size_t)BL * D_INNER * 2);
    unsigned short* dtgb    = (unsigned short*)alloc((size_t)BL * D_INNER * 2);
    unsigned short* ymb     = (unsigned short*)alloc((size_t)BL * D_INNER * 2);
    unsigned short* dtlrb   = (unsigned short*)alloc((size_t)BL * 32 * 2);
    unsigned short* xb      = (unsigned short*)alloc((size_t)BL * DIM * 2);
    unsigned short* W_in_b  = (unsigned short*)alloc((size_t)E2 * DIM * 2);
    unsigned short* W_out_b = (unsigned short*)alloc((size_t)DIM * D_INNER * 2);
    unsigned short* W_x_b   = (unsigned short*)alloc((size_t)64 * D_INNER * 2);
    unsigned short* W_dt_b  = (unsigned short*)alloc((size_t)D_INNER * DT_RANK * 2);
    float* xdbl             = (float*)alloc((size_t)BL * 64 * 4);
    float* part             = (float*)alloc((size_t)XKS * BL * 64 * 4);
    unsigned short* Hc      = (unsigned short*)alloc((size_t)BATCH * NCHUNK * D_INNER * 16 * 2);
    float* sdt              = (float*)alloc((size_t)BATCH * NCHUNK * D_INNER * 4);

    // 0. all f32->bf16 conversions in one dispatch
    cvt5_kernel<<<(294912 + 196608 + 147456 + 12288 + 6144) / 256, 256, 0, stream>>>(
        W_in, W_in_b, E2 * DIM / 8,
        x, xb, BL * DIM / 8,
        W_out, W_out_b, DIM * D_INNER / 8,
        W_x, W_x_b, 64 * D_INNER / 8,
        W_dt, W_dt_b, D_INNER * DT_RANK / 8);
    // 1. xz = x @ W_in^T  (bf16 MFMA -> bf16 out, 128x128 tiles, 384 blocks)
    gemm_bf16<128, 128, 3><<<dim3(E2 / 128, BL / 128), 256, 0, stream>>>(
        xb, W_in_b, xzb, E2, nullptr, 0, DIM);
    // 2. depthwise causal conv + bias + silu (bf16 in/out, 8 ch/thread)
    conv_silu_kernel<<<(BL * D_INNER / 8) / 256, 256, 0, stream>>>(
        xzb, W_conv, b_conv, xcsb);
    // 3. x_dbl split-K MFMA GEMM (pipelined) + reduce
    xdbl_gemm<<<dim3(XKS, BL / 128), 256, 0, stream>>>(xcsb, W_x_b, part);
    xdbl_reduce<<<(BL * 64) / 256, 256, 0, stream>>>(part, xdbl, dtlrb);
    // 4. dt = softplus(dt_lr @ W_dt^T + 2 b_dt) -> bf16  (64x64, 768 blocks)
    gemm_bf16<64, 64, 1><<<dim3(D_INNER / 64, BL / 64), 256, 0, stream>>>(
        dtlrb, W_dt_b, dtgb, D_INNER, b_dt, 0, DT_RANK);
    // 5. 3-pass chunked selective scan (bf16 state, 4-deep pipelined combine)
    scan_p1<<<dim3(D_INNER / 256, NCHUNK, BATCH), 256, 0, stream>>>(
        dtgb, xcsb, xdbl, A_log, Hc, sdt);
    scan_p2<<<(BATCH * D_INNER * 16) / 256, 256, 0, stream>>>(Hc, sdt, A_log);
    scan_p3<<<dim3(D_INNER / 256, NCHUNK, BATCH), 256, 0, stream>>>(
        dtgb, xcsb, xdbl, A_log, Dp, Hc, xzb, ymb);
    // 6. out = ym @ W_out^T + x  (bf16 MFMA, 64x64 tiles, 384 blocks)
    gemm_bf16<64, 64, 2><<<dim3(DIM / 64, BL / 64), 256, 0, stream>>>(
        ymb, W_out_b, out, DIM, x, DIM, D_INNER);
}